// Round 5
// baseline (225.947 us; speedup 1.0000x reference)
//
#include <hip/hip_runtime.h>
#include <hip/hip_bf16.h>
#include <cstdint>
#include <cstddef>

typedef __bf16 bf16_t;
typedef __bf16 bf16x8 __attribute__((ext_vector_type(8)));
typedef __bf16 bf16x4 __attribute__((ext_vector_type(4)));
typedef float f32x4 __attribute__((ext_vector_type(4)));

#define DEVINL static __device__ __forceinline__

constexpr int B_ = 4, S_ = 2048, D_ = 512, H_ = 8, HD_ = 64;
constexpr int M_ = B_ * S_;   // 8192
constexpr int NIN = 14;

DEVINL bf16x8 load8g(const bf16_t* p) { return *reinterpret_cast<const bf16x8*>(p); }

// XOR-swizzle: permute 16B-chunk index by row&7 within each aligned 64-elem group.
// Producers store swizzled; gl2lds stages contiguously; LDS fragment reads use swcol
// -> 2-way banks (free, m136) instead of 16-way on unpadded 128B rows.
DEVINL int swcol(int col, int row) {
  return (col & ~63) | ((((col >> 3) ^ row) & 7) << 3) | (col & 7);
}

// K-specific swizzle: attn reads kf with permuted rows rho whose low bits are
// {l16&3 | bit3}; key the chunk-XOR on row bits {0,1,3} so each 8-lane phase
// group of ds_read_b128 hits 8 distinct 16B chunks (conflict-free).
DEVINL int pK(int row) { return (row & 3) | (((row >> 3) & 1) << 2); }
DEVINL int swcolK(int col, int row) {
  return (col & ~63) | ((((col >> 3) ^ pK(row)) & 7) << 3) | (col & 7);
}

// async global->LDS, 16 B/lane. LDS dest is wave-uniform base + lane*16 (m104/m108).
DEVINL void gl2lds(const bf16_t* g, bf16_t* l) {
  __builtin_amdgcn_global_load_lds(
      (const __attribute__((address_space(1))) void*)g,
      (__attribute__((address_space(3))) void*)l, 16, 0, 0);
}

DEVINL void stage16(bf16_t* dst, const void* src, size_t off, bool f32) {
  if (f32) {
    const float* p = (const float*)src + off;
    bf16x8 v0, v1;
#pragma unroll
    for (int j = 0; j < 8; ++j) { v0[j] = (bf16_t)p[j]; v1[j] = (bf16_t)p[8 + j]; }
    *reinterpret_cast<bf16x8*>(dst)     = v0;
    *reinterpret_cast<bf16x8*>(dst + 8) = v1;
  } else {
    const bf16_t* p = (const bf16_t*)src + off;
    *reinterpret_cast<bf16x8*>(dst)     = load8g(p);
    *reinterpret_cast<bf16x8*>(dst + 8) = load8g(p + 8);
  }
}

DEVINL float readf(const void* p, size_t i, bool f32) {
  return f32 ? ((const float*)p)[i] : (float)((const bf16_t*)p)[i];
}

// ---------------- dtype detect: flags[i]=1 iff input i is float32 ----------------
struct DetectArgs { const uint16_t* p[NIN]; int n[NIN]; int* flags; };

__global__ __launch_bounds__(64) void detect_kernel(DetectArgs a) {
  const int z = blockIdx.x;
  const uint16_t* p = a.p[z];
  const int n = a.n[z];
  const int t = threadIdx.x;
  int cnt = 0;
  for (int i = t; i < n; i += 64) {
    const int e = (p[i] >> 7) & 0xFF;
    cnt += (e >= 200);
  }
#pragma unroll
  for (int off = 32; off > 0; off >>= 1) cnt += __shfl_down(cnt, off, 64);
  if (t == 0) a.flags[z] = (cnt > 16) ? 1 : 0;
}

// -------- cvt: mod features -> packed bf16, SWIZZLED layout (gl2lds consumer) --------
struct CvtArgs { const void* src[2]; bf16_t* dst[2]; int idx[2]; const int* flags; };

__global__ __launch_bounds__(256) void cvt_kernel(CvtArgs a) {
  const int z = blockIdx.y;
  const bool f32 = a.flags[a.idx[z]] != 0;
  const size_t i = ((size_t)blockIdx.x * 256 + threadIdx.x) * 8;
  const int row = (int)(i >> 9);
  const int col = (int)(i & 511);
  bf16_t* dst = a.dst[z] + (size_t)row * 512 + swcol(col, row);
  if (f32) {
    const float* p = (const float*)a.src[z] + i;
    bf16x8 v;
#pragma unroll
    for (int j = 0; j < 8; ++j) v[j] = (bf16_t)p[j];
    *reinterpret_cast<bf16x8*>(dst) = v;
  } else {
    *reinterpret_cast<bf16x8*>(dst) = load8g((const bf16_t*)a.src[z] + i);
  }
}

// -------- weight transpose: WT[n][k] = W[k][n], SWIZZLED output (gl2lds consumer) --------
struct TransArgs { const void* src[6]; int srcIdx[6]; bf16_t* dst[6]; const int* flags; };

__global__ __launch_bounds__(256) void transpose_kernel(TransArgs a) {
  __shared__ bf16_t tile[64][80];
  const int w = blockIdx.z;
  const void* src = a.src[w];
  const bool f32 = a.flags[a.srcIdx[w]] != 0;
  bf16_t* dst = a.dst[w];
  const int k0 = blockIdx.x * 64, n0 = blockIdx.y * 64;
  const int t = threadIdx.x;
  const int r = t >> 2, c0 = (t & 3) * 16;
  stage16(&tile[r][c0], src, (size_t)(k0 + r) * 512 + n0 + c0, f32);
  __syncthreads();
  const int orow = n0 + r;
  bf16_t* o = dst + (size_t)orow * 512;
#pragma unroll
  for (int half = 0; half < 2; ++half) {
    bf16x8 ov;
#pragma unroll
    for (int j = 0; j < 8; ++j) ov[j] = tile[c0 + half * 8 + j][r];
    *reinterpret_cast<bf16x8*>(o + swcol(k0 + c0 + half * 8, orow)) = ov;
  }
}

// ---- plain GEMM + bias, 128x64 tile, BK=64, DOUBLE-BUFFERED staging (1 barrier/iter) ----
struct GemmBatch {
  const bf16_t* A[3];
  const bf16_t* Bt[3];
  const void* bias[3]; int bIdx[3];
  void* C[3];          int cIdx[3];
  const int* flags;
};

__global__ __launch_bounds__(256) void gemm_bt_kernel(GemmBatch args) {
  constexpr int K = 512, N = 512;
  __shared__ bf16_t As[2][128][64];   // 32 KB
  __shared__ bf16_t Bs[2][64][64];    // 16 KB
  const int z = blockIdx.z;
  const bf16_t* Ag  = args.A[z];
  const bf16_t* Btg = args.Bt[z];
  const void* biag  = args.bias[z];
  void* Cg          = args.C[z];
  const bool bf32 = args.bIdx[z] >= 0 && args.flags[args.bIdx[z]];
  const bool cf32 = args.cIdx[z] >= 0 && args.flags[args.cIdx[z]];
  const int m0 = blockIdx.x * 128, n0 = blockIdx.y * 64;
  const int t = threadIdx.x, lane = t & 63, wave = t >> 6;
  const int l16 = lane & 15, quad = lane >> 4;
  const int wm = wave * 32;
  const int lr = lane >> 3, lc = (lane & 7) * 8;   // 8 rows x 128 B per gl2lds

  auto stage = [&](int buf, int k0) {
#pragma unroll
    for (int s = 0; s < 4; ++s) {
      const int r = wm + s * 8;
      gl2lds(Ag + (size_t)(m0 + r + lr) * K + k0 + lc, &As[buf][r][0]);
    }
#pragma unroll
    for (int s = 0; s < 2; ++s) {
      const int r = wave * 16 + s * 8;
      gl2lds(Btg + (size_t)(n0 + r + lr) * K + k0 + lc, &Bs[buf][r][0]);
    }
  };

  f32x4 acc[2][4] = {};
  stage(0, 0);

  for (int kt = 0; kt < K / 64; ++kt) {
    const int cur = kt & 1;
    __syncthreads();                    // drains stage(cur) issued one iter ago
    if (kt + 1 < K / 64) stage(1 - cur, (kt + 1) * 64);   // prefetch next
#pragma unroll
    for (int ks = 0; ks < 2; ++ks) {
      const int sw = swcol(ks * 32 + quad * 8, l16);
      bf16x8 af[2], bfr[4];
#pragma unroll
      for (int i = 0; i < 2; ++i)
        af[i] = *reinterpret_cast<const bf16x8*>(&As[cur][wm + i * 16 + l16][sw]);
#pragma unroll
      for (int j = 0; j < 4; ++j)
        bfr[j] = *reinterpret_cast<const bf16x8*>(&Bs[cur][j * 16 + l16][sw]);
#pragma unroll
      for (int i = 0; i < 2; ++i)
#pragma unroll
        for (int j = 0; j < 4; ++j)
          acc[i][j] = __builtin_amdgcn_mfma_f32_16x16x32_bf16(af[i], bfr[j], acc[i][j], 0, 0, 0);
    }
  }
  // epilogue: + bias. C/D layout: col=lane&15, row=quad*4+reg (m89). C NORMAL layout.
#pragma unroll
  for (int j = 0; j < 4; ++j) {
    const int col = n0 + j * 16 + l16;
    const float bv = readf(biag, col, bf32);
#pragma unroll
    for (int i = 0; i < 2; ++i) {
      const int rowb = m0 + wm + i * 16 + quad * 4;
#pragma unroll
      for (int r = 0; r < 4; ++r) {
        const size_t idx = (size_t)(rowb + r) * N + col;
        const float v = acc[i][j][r] + bv;
        if (cf32) ((float*)Cg)[idx] = v;
        else      ((bf16_t*)Cg)[idx] = (bf16_t)v;
      }
    }
  }
}

// ---- GEMM + fused modulation, 128x64, BK=64, dbuf: z=0 -> Kmod (swK); z=1 -> VtT (sw) ----
struct GemmModArgs {
  const bf16_t* A;        // mod2 bf16 (swizzled)
  const bf16_t* Bt[2];    // wtk, wtv (swizzled)
  const void* bias[2]; int bIdx[2];
  const bf16_t* Sc;       // scale [M,512] bf16, normal layout
  const bf16_t* Sh;       // shift [M,512] bf16, normal layout
  bf16_t* Kmod;           // [M,512] swizzled with swcolK (attn kf consumer)
  bf16_t* VtT;            // [B][H][HD][S] swizzled
  const int* flags;
};

__global__ __launch_bounds__(256) void gemm_mod_kernel(GemmModArgs args) {
  constexpr int K = 512;
  __shared__ bf16_t As[2][128][64];
  __shared__ bf16_t Bs[2][64][64];
  const int z = blockIdx.z;
  const bf16_t* Ag  = args.A;
  const bf16_t* Btg = args.Bt[z];
  const void* biag  = args.bias[z];
  const bool bf32 = args.bIdx[z] >= 0 && args.flags[args.bIdx[z]];
  const int m0 = blockIdx.x * 128, n0 = blockIdx.y * 64;
  const int t = threadIdx.x, lane = t & 63, wave = t >> 6;
  const int l16 = lane & 15, quad = lane >> 4;
  const int wm = wave * 32;
  const int lr = lane >> 3, lc = (lane & 7) * 8;

  auto stage = [&](int buf, int k0) {
#pragma unroll
    for (int s = 0; s < 4; ++s) {
      const int r = wm + s * 8;
      gl2lds(Ag + (size_t)(m0 + r + lr) * K + k0 + lc, &As[buf][r][0]);
    }
#pragma unroll
    for (int s = 0; s < 2; ++s) {
      const int r = wave * 16 + s * 8;
      gl2lds(Btg + (size_t)(n0 + r + lr) * K + k0 + lc, &Bs[buf][r][0]);
    }
  };

  f32x4 acc[2][4] = {};
  stage(0, 0);

  for (int kt = 0; kt < K / 64; ++kt) {
    const int cur = kt & 1;
    __syncthreads();
    if (kt + 1 < K / 64) stage(1 - cur, (kt + 1) * 64);
#pragma unroll
    for (int ks = 0; ks < 2; ++ks) {
      const int sw = swcol(ks * 32 + quad * 8, l16);
      bf16x8 af[2], bfr[4];
#pragma unroll
      for (int i = 0; i < 2; ++i)
        af[i] = *reinterpret_cast<const bf16x8*>(&As[cur][wm + i * 16 + l16][sw]);
#pragma unroll
      for (int j = 0; j < 4; ++j)
        bfr[j] = *reinterpret_cast<const bf16x8*>(&Bs[cur][j * 16 + l16][sw]);
#pragma unroll
      for (int i = 0; i < 2; ++i)
#pragma unroll
        for (int j = 0; j < 4; ++j)
          acc[i][j] = __builtin_amdgcn_mfma_f32_16x16x32_bf16(af[i], bfr[j], acc[i][j], 0, 0, 0);
    }
  }
  // fused epilogue: y = (acc + bias)*scale + shift in fp32, one rounding to bf16
#pragma unroll
  for (int j = 0; j < 4; ++j) {
    const int col = n0 + j * 16 + l16;
    const float bv = readf(biag, col, bf32);
#pragma unroll
    for (int i = 0; i < 2; ++i) {
      const int rowb = m0 + wm + i * 16 + quad * 4;
      if (z == 0) {
#pragma unroll
        for (int r = 0; r < 4; ++r) {
          const int row = rowb + r;
          const size_t idx = (size_t)row * 512 + col;     // sc/sh normal layout
          const float sc = (float)args.Sc[idx], sh = (float)args.Sh[idx];
          args.Kmod[(size_t)row * 512 + swcolK(col, row)] = (bf16_t)fmaf(acc[i][j][r] + bv, sc, sh);
        }
      } else {
        bf16x4 pack;
#pragma unroll
        for (int r = 0; r < 4; ++r) {
          const size_t idx = (size_t)(rowb + r) * 512 + col;
          const float sc = (float)args.Sc[idx], sh = (float)args.Sh[idx];
          pack[r] = (bf16_t)fmaf(acc[i][j][r] + bv, sc, sh);
        }
        const int bb = rowb >> 11;      // batch (2048 rows; tile never crosses batch)
        const int ss = rowb & 2047;     // seq (multiple of 4)
        const int hh = col >> 6, dd = col & 63;
        *reinterpret_cast<bf16x4*>(
            args.VtT + (((size_t)(bb * H_ + hh)) * HD_ + dd) * S_ + swcol(ss, dd)) = pack;
      }
    }
  }
}

// ---- flash attention v13: 32 q/wave (2x LDS-read amortization) + deep pipeline.
// 512 blocks x 256 thr (4 waves x 32 q = 128 q/block); 2 independent blocks/CU so a
// block's barrier wait is covered by the other block. 3-slot K/V LDS ring (48 KB),
// fused {s_waitcnt vmcnt(4); s_barrier}, prefetch distance 2, never drain in loop.
// Per wave per tile: 4 gl2lds (2 K + 2 V row-blocks of 8); steady state 8 outstanding.
// kf[j]/vf[dj] register-reused across both q sub-tiles -> 16 KB LDS reads serve 32 q
// (v12: 16 KB per 16 q). Lane-local P via key-permuted kf, as before.
__global__ __launch_bounds__(256) void attn_kernel(const bf16_t* Q, const bf16_t* Kb,
                                                   const bf16_t* Vt, bf16_t* O) {
  __shared__ bf16_t Ks[3][64][64];    // 24 KB (gl2lds dest, swcolK data)
  __shared__ bf16_t Vs[3][64][64];    // 24 KB (swcol data)
  const int i = blockIdx.x;
  const int xcd = i & 7, g = i >> 3;     // g in 0..63
  const int slice = xcd * 4 + (g & 3);   // (b,h): 4 slices per XCD -> 2 MB KV per XCD L2
  const int qt = g >> 2;                 // 0..15
  const int b = slice >> 3, h = slice & 7;
  const int t = threadIdx.x, wave = t >> 6, lane = t & 63;   // wave 0..3
  const int l16 = lane & 15, quad = lane >> 4;
  const int q0 = qt * 128 + wave * 32;   // 32 q-rows per wave
  const int lr = lane >> 3, lc = (lane & 7) * 8;

  bf16x8 ones;
#pragma unroll
  for (int j = 0; j < 8; ++j) ones[j] = (bf16_t)1.0f;

  bf16x8 qf[2][2];   // q_buf NORMAL layout; [qs][dc]
#pragma unroll
  for (int qs = 0; qs < 2; ++qs) {
    const size_t qrow = ((size_t)b * S_ + q0 + qs * 16 + l16) * D_ + h * HD_;
    qf[qs][0] = load8g(Q + qrow + quad * 8);
    qf[qs][1] = load8g(Q + qrow + 32 + quad * 8);
  }

  f32x4 oacc[2][4] = {};
  f32x4 lacc[2] = {};

  const size_t kbase = (size_t)b * S_ * D_ + h * HD_;
  const size_t vbase = ((size_t)(b * H_ + h)) * HD_ * S_;

  // precomputed kf offsets: lane l16 of kf[j] reads local row rho(j,l16)
  const int rbase = ((l16 >> 2) << 3) | (l16 & 3);
  int koff[2][4];   // [dc][j], element offset within 64x64 tile
#pragma unroll
  for (int j = 0; j < 4; ++j) {
    const int rho = rbase + (j >> 1) * 32 + (j & 1) * 4;
#pragma unroll
    for (int dc = 0; dc < 2; ++dc)
      koff[dc][j] = rho * 64 + swcolK(dc * 32 + quad * 8, rho);
  }
  const int voff[2] = { swcol(quad * 8, l16), swcol(32 + quad * 8, l16) };

  // 4 waves x 16 rows = 64 rows; 2 K + 2 V gl2lds per wave per tile
  auto stage = [&](int slot, int k0) {
#pragma unroll
    for (int s = 0; s < 2; ++s) {
      const int r = wave * 16 + s * 8;
      gl2lds(Kb + kbase + (size_t)(k0 + r + lr) * D_ + lc, &Ks[slot][r][0]);
      gl2lds(Vt + vbase + (size_t)(r + lr) * S_ + k0 + lc, &Vs[slot][r][0]);
    }
  };

  constexpr float CE = 0.18033688011112042f;  // 0.125 * log2(e)

  auto compute = [&](int cur) {
    // ---- S^T (key-permuted): sacc[j][qs] reg r = S[(j>>1)*32 + quad*8 + (j&1)*4 + r][q] ----
    f32x4 sacc[4][2] = {};
    const bf16_t* ksbase = &Ks[cur][0][0];
#pragma unroll
    for (int dc = 0; dc < 2; ++dc) {
      bf16x8 kf[4];
#pragma unroll
      for (int j = 0; j < 4; ++j)
        kf[j] = *reinterpret_cast<const bf16x8*>(ksbase + koff[dc][j]);
#pragma unroll
      for (int j = 0; j < 4; ++j)
#pragma unroll
        for (int qs = 0; qs < 2; ++qs)
          sacc[j][qs] = __builtin_amdgcn_mfma_f32_16x16x32_bf16(kf[j], qf[qs][dc], sacc[j][qs], 0, 0, 0);
    }
    // ---- P = exp2(min(s*CE, 57.5)) lane-local -> feeds PV B-operand directly ----
#pragma unroll
    for (int kc = 0; kc < 2; ++kc) {
      bf16x8 vf[4];
#pragma unroll
      for (int dj = 0; dj < 4; ++dj)
        vf[dj] = *reinterpret_cast<const bf16x8*>(&Vs[cur][dj * 16 + l16][voff[kc]]);
#pragma unroll
      for (int qs = 0; qs < 2; ++qs) {
        bf16x8 bp;
#pragma unroll
        for (int r = 0; r < 4; ++r) {
          bp[r]     = (bf16_t)__builtin_amdgcn_exp2f(fminf(sacc[kc * 2][qs][r]     * CE, 57.5f));
          bp[4 + r] = (bf16_t)__builtin_amdgcn_exp2f(fminf(sacc[kc * 2 + 1][qs][r] * CE, 57.5f));
        }
#pragma unroll
        for (int dj = 0; dj < 4; ++dj)
          oacc[qs][dj] = __builtin_amdgcn_mfma_f32_16x16x32_bf16(vf[dj], bp, oacc[qs][dj], 0, 0, 0);
        lacc[qs] = __builtin_amdgcn_mfma_f32_16x16x32_bf16(ones, bp, lacc[qs], 0, 0, 0);
      }
    }
  };

  // drain Q loads once so the loop's vmcnt ledger counts only gl2lds ops
  asm volatile("s_waitcnt vmcnt(0)" ::: "memory");
  // prologue: tiles 0 and 1 in flight (8 VMEM ops/wave)
  stage(0, 0);
  stage(1, 64);

  constexpr int NT = S_ / 64;   // 32
  int cur = 0;
  for (int kt = 0; kt < NT - 1; ++kt) {
    // wait stage(kt) done; stage(kt+1) [4 ops] stays in flight.
    asm volatile("s_waitcnt vmcnt(4)\n\ts_barrier" ::: "memory");
    __builtin_amdgcn_sched_barrier(0);
    if (kt + 2 < NT) {
      const int slot2 = cur == 0 ? 2 : cur - 1;   // (kt+2)%3, freed at barrier above
      stage(slot2, (kt + 2) * 64);
    }
    compute(cur);
    cur = (cur == 2) ? 0 : cur + 1;
  }
  // last tile: only stage(NT-1) outstanding -> full drain
  asm volatile("s_waitcnt vmcnt(0)\n\ts_barrier" ::: "memory");
  __builtin_amdgcn_sched_barrier(0);
  compute(cur);

  // ---- epilogue: O[q][d] = O^T[d][q] / l[q]; packed 8B stores, SWIZZLED (feeds g2) ----
#pragma unroll
  for (int qs = 0; qs < 2; ++qs) {
    const float linv = 1.0f / fmaxf(lacc[qs][0], 1e-30f);
    const int q = q0 + qs * 16 + l16;
    const size_t orow = ((size_t)b * S_ + q) * D_ + h * HD_;
#pragma unroll
    for (int dj = 0; dj < 4; ++dj) {
      bf16x4 pack;
#pragma unroll
      for (int r = 0; r < 4; ++r) pack[r] = (bf16_t)(oacc[qs][dj][r] * linv);
      *reinterpret_cast<bf16x4*>(&O[orow + swcol(dj * 16 + quad * 4, q)]) = pack;
    }
  }
}

// ---------------- host launcher ----------------
extern "C" void kernel_launch(void* const* d_in, const int* in_sizes, int n_in,
                              void* d_out, int out_size, void* d_ws, size_t ws_size,
                              hipStream_t stream) {
  (void)n_in; (void)out_size; (void)ws_size;

  char* ws = (char*)d_ws;
  auto alloc = [&](size_t bytes) -> char* {
    char* p = ws; ws += (bytes + 255) & ~(size_t)255; return p;
  };
  int* flags = (int*)alloc(64 * sizeof(int));
  const size_t wbytes = (size_t)512 * 512 * sizeof(bf16_t);
  const size_t fbytes = (size_t)M_ * D_ * sizeof(bf16_t);
  bf16_t* wt    = (bf16_t*)alloc(6 * wbytes);  // 3 MB (swizzled)
  bf16_t* m1b   = (bf16_t*)alloc(fbytes);      // 8 MB mod1 bf16 swizzled; vtb alias after g1a
  bf16_t* m2b   = (bf16_t*)alloc(fbytes);      // 8 MB mod2 bf16 swizzled
  bf16_t* q_buf = (bf16_t*)alloc(fbytes);      // 8 MB normal
  bf16_t* stmp  = (bf16_t*)alloc(fbytes);      // 8 MB normal; attn_b alias after g1b
  bf16_t* shtmp = (bf16_t*)alloc(fbytes);      // 8 MB normal
  bf16_t* kmod  = (bf16_t*)alloc(fbytes);      // 8 MB swizzled (swcolK)
  bf16_t* vtb    = m1b;    // alias: m1b dead after g1a
  bf16_t* attn_b = stmp;   // alias: stmp dead after g1b epilogue

  bf16_t* wtq  = wt + 0 * 512 * 512;
  bf16_t* wtk  = wt + 1 * 512 * 512;
  bf16_t* wtv  = wt + 2 * 512 * 512;
  bf16_t* wts  = wt + 3 * 512 * 512;
  bf16_t* wtsh = wt + 4 * 512 * 512;
  bf16_t* wto  = wt + 5 * 512 * 512;

  DetectArgs da;
  for (int i = 0; i < NIN; ++i) {
    da.p[i] = (const uint16_t*)d_in[i];
    da.n[i] = in_sizes[i] < 2048 ? in_sizes[i] : 2048;
  }
  da.flags = flags;
  hipLaunchKernelGGL(detect_kernel, dim3(NIN), dim3(64), 0, stream, da);

  CvtArgs ca;
  ca.src[0] = d_in[0]; ca.dst[0] = m1b; ca.idx[0] = 0;
  ca.src[1] = d_in[1]; ca.dst[1] = m2b; ca.idx[1] = 1;
  ca.flags = flags;
  hipLaunchKernelGGL(cvt_kernel, dim3(M_ * D_ / 2048, 2), dim3(256), 0, stream, ca);

  TransArgs ta;
  const int widx[6] = {2, 4, 6, 10, 12, 8};
  bf16_t* wdst[6] = {wtq, wtk, wtv, wts, wtsh, wto};
  for (int i = 0; i < 6; ++i) { ta.src[i] = d_in[widx[i]]; ta.srcIdx[i] = widx[i]; ta.dst[i] = wdst[i]; }
  ta.flags = flags;
  hipLaunchKernelGGL(transpose_kernel, dim3(8, 8, 6), dim3(256), 0, stream, ta);

  // g1a: Q, scale, shift projections — 1536 blocks, dbuf staging
  GemmBatch g1;
  g1.A[0] = m1b; g1.A[1] = m2b; g1.A[2] = m2b;
  g1.Bt[0] = wtq; g1.Bt[1] = wts; g1.Bt[2] = wtsh;
  g1.bias[0] = d_in[3];  g1.bIdx[0] = 3;
  g1.bias[1] = d_in[11]; g1.bIdx[1] = 11;
  g1.bias[2] = d_in[13]; g1.bIdx[2] = 13;
  g1.C[0] = q_buf; g1.cIdx[0] = -1;
  g1.C[1] = stmp;  g1.cIdx[1] = -1;
  g1.C[2] = shtmp; g1.cIdx[2] = -1;
  g1.flags = flags;
  hipLaunchKernelGGL(gemm_bt_kernel, dim3(M_ / 128, 8, 3), dim3(256), 0, stream, g1);

  // g1b: K, V projections + fused modulation — 1024 blocks, dbuf staging
  GemmModArgs gm;
  gm.A = m2b;
  gm.Bt[0] = wtk; gm.Bt[1] = wtv;
  gm.bias[0] = d_in[5]; gm.bIdx[0] = 5;
  gm.bias[1] = d_in[7]; gm.bIdx[1] = 7;
  gm.Sc = stmp; gm.Sh = shtmp;
  gm.Kmod = kmod; gm.VtT = vtb;
  gm.flags = flags;
  hipLaunchKernelGGL(gemm_mod_kernel, dim3(M_ / 128, 8, 2), dim3(256), 0, stream, gm);

  // attn: 512 blocks x 256 threads (32 q/wave), 3-slot deep pipeline, counted vmcnt
  hipLaunchKernelGGL(attn_kernel, dim3(512), dim3(256), 0, stream,
                     q_buf, kmod, vtb, attn_b);

  // g2: out = attn @ Wo^T + bo — 512 blocks, dbuf staging
  GemmBatch g2;
  for (int i = 0; i < 3; ++i) {
    g2.A[i] = attn_b;
    g2.Bt[i] = wto;
    g2.bias[i] = d_in[9]; g2.bIdx[i] = 9;
    g2.C[i] = d_out; g2.cIdx[i] = 0;
  }
  g2.flags = flags;
  hipLaunchKernelGGL(gemm_bt_kernel, dim3(M_ / 128, 8, 1), dim3(256), 0, stream, g2);
}

// Round 6
// 215.281 us; speedup vs baseline: 1.0495x; 1.0495x over previous
//
#include <hip/hip_runtime.h>
#include <hip/hip_bf16.h>
#include <cstdint>
#include <cstddef>

typedef __bf16 bf16_t;
typedef __bf16 bf16x8 __attribute__((ext_vector_type(8)));
typedef __bf16 bf16x4 __attribute__((ext_vector_type(4)));
typedef float f32x4 __attribute__((ext_vector_type(4)));

#define DEVINL static __device__ __forceinline__

constexpr int B_ = 4, S_ = 2048, D_ = 512, H_ = 8, HD_ = 64;
constexpr int M_ = B_ * S_;   // 8192
constexpr int NIN = 14;

DEVINL bf16x8 load8g(const bf16_t* p) { return *reinterpret_cast<const bf16x8*>(p); }

// XOR-swizzle: permute 16B-chunk index by row&7 within each aligned 64-elem group.
DEVINL int swcol(int col, int row) {
  return (col & ~63) | ((((col >> 3) ^ row) & 7) << 3) | (col & 7);
}

// K-specific swizzle keyed on row bits {0,1,3} (attn kf reads permuted rows).
DEVINL int pK(int row) { return (row & 3) | (((row >> 3) & 1) << 2); }
DEVINL int swcolK(int col, int row) {
  return (col & ~63) | ((((col >> 3) ^ pK(row)) & 7) << 3) | (col & 7);
}

// async global->LDS, 16 B/lane. LDS dest is wave-uniform base + lane*16 (m104/m108).
DEVINL void gl2lds(const bf16_t* g, bf16_t* l) {
  __builtin_amdgcn_global_load_lds(
      (const __attribute__((address_space(1))) void*)g,
      (__attribute__((address_space(3))) void*)l, 16, 0, 0);
}

DEVINL void stage16(bf16_t* dst, const void* src, size_t off, bool f32) {
  if (f32) {
    const float* p = (const float*)src + off;
    bf16x8 v0, v1;
#pragma unroll
    for (int j = 0; j < 8; ++j) { v0[j] = (bf16_t)p[j]; v1[j] = (bf16_t)p[8 + j]; }
    *reinterpret_cast<bf16x8*>(dst)     = v0;
    *reinterpret_cast<bf16x8*>(dst + 8) = v1;
  } else {
    const bf16_t* p = (const bf16_t*)src + off;
    *reinterpret_cast<bf16x8*>(dst)     = load8g(p);
    *reinterpret_cast<bf16x8*>(dst + 8) = load8g(p + 8);
  }
}

DEVINL float readf(const void* p, size_t i, bool f32) {
  return f32 ? ((const float*)p)[i] : (float)((const bf16_t*)p)[i];
}

// ---------------- dtype detect: flags[i]=1 iff input i is float32 ----------------
struct DetectArgs { const uint16_t* p[NIN]; int n[NIN]; int* flags; };

__global__ __launch_bounds__(64) void detect_kernel(DetectArgs a) {
  const int z = blockIdx.x;
  const uint16_t* p = a.p[z];
  const int n = a.n[z];
  const int t = threadIdx.x;
  int cnt = 0;
  for (int i = t; i < n; i += 64) {
    const int e = (p[i] >> 7) & 0xFF;
    cnt += (e >= 200);
  }
#pragma unroll
  for (int off = 32; off > 0; off >>= 1) cnt += __shfl_down(cnt, off, 64);
  if (t == 0) a.flags[z] = (cnt > 16) ? 1 : 0;
}

// -------- cvt: mod features -> packed bf16, SWIZZLED layout (gl2lds consumer) --------
struct CvtArgs { const void* src[2]; bf16_t* dst[2]; int idx[2]; const int* flags; };

__global__ __launch_bounds__(256) void cvt_kernel(CvtArgs a) {
  const int z = blockIdx.y;
  const bool f32 = a.flags[a.idx[z]] != 0;
  const size_t i = ((size_t)blockIdx.x * 256 + threadIdx.x) * 8;
  const int row = (int)(i >> 9);
  const int col = (int)(i & 511);
  bf16_t* dst = a.dst[z] + (size_t)row * 512 + swcol(col, row);
  if (f32) {
    const float* p = (const float*)a.src[z] + i;
    bf16x8 v;
#pragma unroll
    for (int j = 0; j < 8; ++j) v[j] = (bf16_t)p[j];
    *reinterpret_cast<bf16x8*>(dst) = v;
  } else {
    *reinterpret_cast<bf16x8*>(dst) = load8g((const bf16_t*)a.src[z] + i);
  }
}

// -------- weight transpose: WT[n][k] = W[k][n], SWIZZLED output (gl2lds consumer) --------
struct TransArgs { const void* src[6]; int srcIdx[6]; bf16_t* dst[6]; const int* flags; };

__global__ __launch_bounds__(256) void transpose_kernel(TransArgs a) {
  __shared__ bf16_t tile[64][80];
  const int w = blockIdx.z;
  const void* src = a.src[w];
  const bool f32 = a.flags[a.srcIdx[w]] != 0;
  bf16_t* dst = a.dst[w];
  const int k0 = blockIdx.x * 64, n0 = blockIdx.y * 64;
  const int t = threadIdx.x;
  const int r = t >> 2, c0 = (t & 3) * 16;
  stage16(&tile[r][c0], src, (size_t)(k0 + r) * 512 + n0 + c0, f32);
  __syncthreads();
  const int orow = n0 + r;
  bf16_t* o = dst + (size_t)orow * 512;
#pragma unroll
  for (int half = 0; half < 2; ++half) {
    bf16x8 ov;
#pragma unroll
    for (int j = 0; j < 8; ++j) ov[j] = tile[c0 + half * 8 + j][r];
    *reinterpret_cast<bf16x8*>(o + swcol(k0 + c0 + half * 8, orow)) = ov;
  }
}

// ---- GEMM + bias, 128x64 tile, BK=64, 512 thr / 8 waves (16-row strip per wave).
// 3-slot LDS ring (72 KB -> 2 blocks/CU = 4 waves/SIMD), fused {s_waitcnt vmcnt(3);
// s_barrier}, prefetch distance 2, never drain in loop (proven in attn v12: -23%).
// 3 gl2lds/wave/tile (2 A + 1 B). Flag/bias reads AFTER final drain (vmcnt ledger). ----
struct GemmBatch {
  const bf16_t* A[3];
  const bf16_t* Bt[3];
  const void* bias[3]; int bIdx[3];
  void* C[3];          int cIdx[3];
  const int* flags;
};

__global__ __launch_bounds__(512) void gemm_bt_kernel(GemmBatch args) {
  constexpr int K = 512, N = 512;
  __shared__ bf16_t As[3][128][64];   // 48 KB
  __shared__ bf16_t Bs[3][64][64];    // 24 KB
  const int z = blockIdx.z;
  const bf16_t* Ag  = args.A[z];
  const bf16_t* Btg = args.Bt[z];
  const int m0 = blockIdx.x * 128, n0 = blockIdx.y * 64;
  const int t = threadIdx.x, lane = t & 63, wave = t >> 6;   // wave 0..7
  const int l16 = lane & 15, quad = lane >> 4;
  const int wm = wave * 16;
  const int lr = lane >> 3, lc = (lane & 7) * 8;   // 8 rows x 128 B per gl2lds

  auto stage = [&](int slot, int k0) {
#pragma unroll
    for (int s = 0; s < 2; ++s) {
      const int r = wm + s * 8;
      gl2lds(Ag + (size_t)(m0 + r + lr) * K + k0 + lc, &As[slot][r][0]);
    }
    gl2lds(Btg + (size_t)(n0 + wave * 8 + lr) * K + k0 + lc, &Bs[slot][wave * 8][0]);
  };

  f32x4 acc[4] = {};

  stage(0, 0);
  stage(1, 64);

  constexpr int NT = K / 64;   // 8
  int cur = 0;
  for (int kt = 0; kt < NT - 1; ++kt) {
    asm volatile("s_waitcnt vmcnt(3)\n\ts_barrier" ::: "memory");
    __builtin_amdgcn_sched_barrier(0);
    if (kt + 2 < NT) {
      const int slot2 = cur == 0 ? 2 : cur - 1;
      stage(slot2, (kt + 2) * 64);
    }
#pragma unroll
    for (int ks = 0; ks < 2; ++ks) {
      const int sw = swcol(ks * 32 + quad * 8, l16);
      bf16x8 af = *reinterpret_cast<const bf16x8*>(&As[cur][wm + l16][sw]);
      bf16x8 bfr[4];
#pragma unroll
      for (int j = 0; j < 4; ++j)
        bfr[j] = *reinterpret_cast<const bf16x8*>(&Bs[cur][j * 16 + l16][sw]);
#pragma unroll
      for (int j = 0; j < 4; ++j)
        acc[j] = __builtin_amdgcn_mfma_f32_16x16x32_bf16(af, bfr[j], acc[j], 0, 0, 0);
    }
    cur = (cur == 2) ? 0 : cur + 1;
  }
  asm volatile("s_waitcnt vmcnt(0)\n\ts_barrier" ::: "memory");
  __builtin_amdgcn_sched_barrier(0);
#pragma unroll
  for (int ks = 0; ks < 2; ++ks) {
    const int sw = swcol(ks * 32 + quad * 8, l16);
    bf16x8 af = *reinterpret_cast<const bf16x8*>(&As[cur][wm + l16][sw]);
    bf16x8 bfr[4];
#pragma unroll
    for (int j = 0; j < 4; ++j)
      bfr[j] = *reinterpret_cast<const bf16x8*>(&Bs[cur][j * 16 + l16][sw]);
#pragma unroll
    for (int j = 0; j < 4; ++j)
      acc[j] = __builtin_amdgcn_mfma_f32_16x16x32_bf16(af, bfr[j], acc[j], 0, 0, 0);
  }

  // epilogue (flags read only now -> no VMEM during loop besides gl2lds)
  const void* biag = args.bias[z];
  void* Cg         = args.C[z];
  const bool bf32 = args.bIdx[z] >= 0 && args.flags[args.bIdx[z]];
  const bool cf32 = args.cIdx[z] >= 0 && args.flags[args.cIdx[z]];
#pragma unroll
  for (int j = 0; j < 4; ++j) {
    const int col = n0 + j * 16 + l16;
    const float bv = readf(biag, col, bf32);
    const int rowb = m0 + wm + quad * 4;
#pragma unroll
    for (int r = 0; r < 4; ++r) {
      const size_t idx = (size_t)(rowb + r) * N + col;
      const float v = acc[j][r] + bv;
      if (cf32) ((float*)Cg)[idx] = v;
      else      ((bf16_t*)Cg)[idx] = (bf16_t)v;
    }
  }
}

// ---- GEMM + fused modulation, same 512-thr 3-slot pipeline; z=0 -> Kmod (swK); z=1 -> VtT ----
struct GemmModArgs {
  const bf16_t* A;        // mod2 bf16 (swizzled)
  const bf16_t* Bt[2];    // wtk, wtv (swizzled)
  const void* bias[2]; int bIdx[2];
  const bf16_t* Sc;       // scale [M,512] bf16, normal layout
  const bf16_t* Sh;       // shift [M,512] bf16, normal layout
  bf16_t* Kmod;           // [M,512] swizzled with swcolK (attn kf consumer)
  bf16_t* VtT;            // [B][H][HD][S] swizzled
  const int* flags;
};

__global__ __launch_bounds__(512) void gemm_mod_kernel(GemmModArgs args) {
  constexpr int K = 512;
  __shared__ bf16_t As[3][128][64];
  __shared__ bf16_t Bs[3][64][64];
  const int z = blockIdx.z;
  const bf16_t* Ag  = args.A;
  const bf16_t* Btg = args.Bt[z];
  const int m0 = blockIdx.x * 128, n0 = blockIdx.y * 64;
  const int t = threadIdx.x, lane = t & 63, wave = t >> 6;
  const int l16 = lane & 15, quad = lane >> 4;
  const int wm = wave * 16;
  const int lr = lane >> 3, lc = (lane & 7) * 8;

  auto stage = [&](int slot, int k0) {
#pragma unroll
    for (int s = 0; s < 2; ++s) {
      const int r = wm + s * 8;
      gl2lds(Ag + (size_t)(m0 + r + lr) * K + k0 + lc, &As[slot][r][0]);
    }
    gl2lds(Btg + (size_t)(n0 + wave * 8 + lr) * K + k0 + lc, &Bs[slot][wave * 8][0]);
  };

  f32x4 acc[4] = {};

  stage(0, 0);
  stage(1, 64);

  constexpr int NT = K / 64;   // 8
  int cur = 0;
  for (int kt = 0; kt < NT - 1; ++kt) {
    asm volatile("s_waitcnt vmcnt(3)\n\ts_barrier" ::: "memory");
    __builtin_amdgcn_sched_barrier(0);
    if (kt + 2 < NT) {
      const int slot2 = cur == 0 ? 2 : cur - 1;
      stage(slot2, (kt + 2) * 64);
    }
#pragma unroll
    for (int ks = 0; ks < 2; ++ks) {
      const int sw = swcol(ks * 32 + quad * 8, l16);
      bf16x8 af = *reinterpret_cast<const bf16x8*>(&As[cur][wm + l16][sw]);
      bf16x8 bfr[4];
#pragma unroll
      for (int j = 0; j < 4; ++j)
        bfr[j] = *reinterpret_cast<const bf16x8*>(&Bs[cur][j * 16 + l16][sw]);
#pragma unroll
      for (int j = 0; j < 4; ++j)
        acc[j] = __builtin_amdgcn_mfma_f32_16x16x32_bf16(af, bfr[j], acc[j], 0, 0, 0);
    }
    cur = (cur == 2) ? 0 : cur + 1;
  }
  asm volatile("s_waitcnt vmcnt(0)\n\ts_barrier" ::: "memory");
  __builtin_amdgcn_sched_barrier(0);
#pragma unroll
  for (int ks = 0; ks < 2; ++ks) {
    const int sw = swcol(ks * 32 + quad * 8, l16);
    bf16x8 af = *reinterpret_cast<const bf16x8*>(&As[cur][wm + l16][sw]);
    bf16x8 bfr[4];
#pragma unroll
    for (int j = 0; j < 4; ++j)
      bfr[j] = *reinterpret_cast<const bf16x8*>(&Bs[cur][j * 16 + l16][sw]);
#pragma unroll
    for (int j = 0; j < 4; ++j)
      acc[j] = __builtin_amdgcn_mfma_f32_16x16x32_bf16(af, bfr[j], acc[j], 0, 0, 0);
  }

  // fused epilogue: y = (acc + bias)*scale + shift in fp32, one rounding to bf16
  const void* biag = args.bias[z];
  const bool bf32 = args.bIdx[z] >= 0 && args.flags[args.bIdx[z]];
#pragma unroll
  for (int j = 0; j < 4; ++j) {
    const int col = n0 + j * 16 + l16;
    const float bv = readf(biag, col, bf32);
    const int rowb = m0 + wm + quad * 4;
    if (z == 0) {
#pragma unroll
      for (int r = 0; r < 4; ++r) {
        const int row = rowb + r;
        const size_t idx = (size_t)row * 512 + col;     // sc/sh normal layout
        const float sc = (float)args.Sc[idx], sh = (float)args.Sh[idx];
        args.Kmod[(size_t)row * 512 + swcolK(col, row)] = (bf16_t)fmaf(acc[j][r] + bv, sc, sh);
      }
    } else {
      bf16x4 pack;
#pragma unroll
      for (int r = 0; r < 4; ++r) {
        const size_t idx = (size_t)(rowb + r) * 512 + col;
        const float sc = (float)args.Sc[idx], sh = (float)args.Sh[idx];
        pack[r] = (bf16_t)fmaf(acc[j][r] + bv, sc, sh);
      }
      const int bb = rowb >> 11;      // batch (2048 rows; tile never crosses batch)
      const int ss = rowb & 2047;     // seq (multiple of 4)
      const int hh = col >> 6, dd = col & 63;
      *reinterpret_cast<bf16x4*>(
          args.VtT + (((size_t)(bb * H_ + hh)) * HD_ + dd) * S_ + swcol(ss, dd)) = pack;
    }
  }
}

// ---- flash attention v12 (proven 46.9 us): 512 blocks x 512 thr (8 waves x 16 q).
// 3-slot K/V LDS ring (48 KB), fused {s_waitcnt vmcnt(2); s_barrier}, prefetch dist 2.
// Lane-local P via key-permuted kf. Q drained pre-loop so vmcnt counts only gl2lds. ----
__global__ __launch_bounds__(512) void attn_kernel(const bf16_t* Q, const bf16_t* Kb,
                                                   const bf16_t* Vt, bf16_t* O) {
  __shared__ bf16_t Ks[3][64][64];    // 24 KB (gl2lds dest, swcolK data)
  __shared__ bf16_t Vs[3][64][64];    // 24 KB (swcol data)
  const int i = blockIdx.x;
  const int xcd = i & 7, g = i >> 3;     // g in 0..63
  const int slice = xcd * 4 + (g & 3);   // (b,h): 4 slices per XCD
  const int qt = g >> 2;                 // 0..15
  const int b = slice >> 3, h = slice & 7;
  const int t = threadIdx.x, wave = t >> 6, lane = t & 63;   // wave 0..7
  const int l16 = lane & 15, quad = lane >> 4;
  const int q0 = qt * 128 + wave * 16;   // 16 q-rows per wave
  const int lr = lane >> 3, lc = (lane & 7) * 8;

  bf16x8 ones;
#pragma unroll
  for (int j = 0; j < 8; ++j) ones[j] = (bf16_t)1.0f;

  bf16x8 qf[2];   // q_buf NORMAL layout; [dc]
  {
    const size_t qrow = ((size_t)b * S_ + q0 + l16) * D_ + h * HD_;
    qf[0] = load8g(Q + qrow + quad * 8);
    qf[1] = load8g(Q + qrow + 32 + quad * 8);
  }

  f32x4 oacc[4] = {};
  f32x4 lacc = {};

  const size_t kbase = (size_t)b * S_ * D_ + h * HD_;
  const size_t vbase = ((size_t)(b * H_ + h)) * HD_ * S_;

  const int rbase = ((l16 >> 2) << 3) | (l16 & 3);
  int koff[2][4];   // [dc][j]
#pragma unroll
  for (int j = 0; j < 4; ++j) {
    const int rho = rbase + (j >> 1) * 32 + (j & 1) * 4;
#pragma unroll
    for (int dc = 0; dc < 2; ++dc)
      koff[dc][j] = rho * 64 + swcolK(dc * 32 + quad * 8, rho);
  }
  const int voff[2] = { swcol(quad * 8, l16), swcol(32 + quad * 8, l16) };

  auto stage = [&](int slot, int k0) {
    const int r = wave * 8;
    gl2lds(Kb + kbase + (size_t)(k0 + r + lr) * D_ + lc, &Ks[slot][r][0]);
    gl2lds(Vt + vbase + (size_t)(r + lr) * S_ + k0 + lc, &Vs[slot][r][0]);
  };

  constexpr float CE = 0.18033688011112042f;  // 0.125 * log2(e)

  auto compute = [&](int cur) {
    f32x4 sacc[4] = {};
    const bf16_t* ksbase = &Ks[cur][0][0];
#pragma unroll
    for (int dc = 0; dc < 2; ++dc) {
      bf16x8 kf[4];
#pragma unroll
      for (int j = 0; j < 4; ++j)
        kf[j] = *reinterpret_cast<const bf16x8*>(ksbase + koff[dc][j]);
#pragma unroll
      for (int j = 0; j < 4; ++j)
        sacc[j] = __builtin_amdgcn_mfma_f32_16x16x32_bf16(kf[j], qf[dc], sacc[j], 0, 0, 0);
    }
#pragma unroll
    for (int kc = 0; kc < 2; ++kc) {
      bf16x8 vf[4];
#pragma unroll
      for (int dj = 0; dj < 4; ++dj)
        vf[dj] = *reinterpret_cast<const bf16x8*>(&Vs[cur][dj * 16 + l16][voff[kc]]);
      bf16x8 bp;
#pragma unroll
      for (int r = 0; r < 4; ++r) {
        bp[r]     = (bf16_t)__builtin_amdgcn_exp2f(fminf(sacc[kc * 2][r]     * CE, 57.5f));
        bp[4 + r] = (bf16_t)__builtin_amdgcn_exp2f(fminf(sacc[kc * 2 + 1][r] * CE, 57.5f));
      }
#pragma unroll
      for (int dj = 0; dj < 4; ++dj)
        oacc[dj] = __builtin_amdgcn_mfma_f32_16x16x32_bf16(vf[dj], bp, oacc[dj], 0, 0, 0);
      lacc = __builtin_amdgcn_mfma_f32_16x16x32_bf16(ones, bp, lacc, 0, 0, 0);
    }
  };

  // drain Q loads once so the loop's vmcnt ledger counts only gl2lds ops
  asm volatile("s_waitcnt vmcnt(0)" ::: "memory");
  stage(0, 0);
  stage(1, 64);

  constexpr int NT = S_ / 64;   // 32
  int cur = 0;
  for (int kt = 0; kt < NT - 1; ++kt) {
    asm volatile("s_waitcnt vmcnt(2)\n\ts_barrier" ::: "memory");
    __builtin_amdgcn_sched_barrier(0);
    if (kt + 2 < NT) {
      const int slot2 = cur == 0 ? 2 : cur - 1;   // (kt+2)%3, freed at barrier above
      stage(slot2, (kt + 2) * 64);
    }
    compute(cur);
    cur = (cur == 2) ? 0 : cur + 1;
  }
  asm volatile("s_waitcnt vmcnt(0)\n\ts_barrier" ::: "memory");
  __builtin_amdgcn_sched_barrier(0);
  compute(cur);

  // ---- epilogue: O[q][d] = O^T[d][q] / l[q]; packed 8B stores, SWIZZLED (feeds g2) ----
  {
    const float linv = 1.0f / fmaxf(lacc[0], 1e-30f);
    const int q = q0 + l16;
    const size_t orow = ((size_t)b * S_ + q) * D_ + h * HD_;
#pragma unroll
    for (int dj = 0; dj < 4; ++dj) {
      bf16x4 pack;
#pragma unroll
      for (int r = 0; r < 4; ++r) pack[r] = (bf16_t)(oacc[dj][r] * linv);
      *reinterpret_cast<bf16x4*>(&O[orow + swcol(dj * 16 + quad * 4, q)]) = pack;
    }
  }
}

// ---------------- host launcher ----------------
extern "C" void kernel_launch(void* const* d_in, const int* in_sizes, int n_in,
                              void* d_out, int out_size, void* d_ws, size_t ws_size,
                              hipStream_t stream) {
  (void)n_in; (void)out_size; (void)ws_size;

  char* ws = (char*)d_ws;
  auto alloc = [&](size_t bytes) -> char* {
    char* p = ws; ws += (bytes + 255) & ~(size_t)255; return p;
  };
  int* flags = (int*)alloc(64 * sizeof(int));
  const size_t wbytes = (size_t)512 * 512 * sizeof(bf16_t);
  const size_t fbytes = (size_t)M_ * D_ * sizeof(bf16_t);
  bf16_t* wt    = (bf16_t*)alloc(6 * wbytes);  // 3 MB (swizzled)
  bf16_t* m1b   = (bf16_t*)alloc(fbytes);      // 8 MB mod1 bf16 swizzled; vtb alias after g1a
  bf16_t* m2b   = (bf16_t*)alloc(fbytes);      // 8 MB mod2 bf16 swizzled
  bf16_t* q_buf = (bf16_t*)alloc(fbytes);      // 8 MB normal
  bf16_t* stmp  = (bf16_t*)alloc(fbytes);      // 8 MB normal; attn_b alias after g1b
  bf16_t* shtmp = (bf16_t*)alloc(fbytes);      // 8 MB normal
  bf16_t* kmod  = (bf16_t*)alloc(fbytes);      // 8 MB swizzled (swcolK)
  bf16_t* vtb    = m1b;    // alias: m1b dead after g1a
  bf16_t* attn_b = stmp;   // alias: stmp dead after g1b epilogue

  bf16_t* wtq  = wt + 0 * 512 * 512;
  bf16_t* wtk  = wt + 1 * 512 * 512;
  bf16_t* wtv  = wt + 2 * 512 * 512;
  bf16_t* wts  = wt + 3 * 512 * 512;
  bf16_t* wtsh = wt + 4 * 512 * 512;
  bf16_t* wto  = wt + 5 * 512 * 512;

  DetectArgs da;
  for (int i = 0; i < NIN; ++i) {
    da.p[i] = (const uint16_t*)d_in[i];
    da.n[i] = in_sizes[i] < 2048 ? in_sizes[i] : 2048;
  }
  da.flags = flags;
  hipLaunchKernelGGL(detect_kernel, dim3(NIN), dim3(64), 0, stream, da);

  CvtArgs ca;
  ca.src[0] = d_in[0]; ca.dst[0] = m1b; ca.idx[0] = 0;
  ca.src[1] = d_in[1]; ca.dst[1] = m2b; ca.idx[1] = 1;
  ca.flags = flags;
  hipLaunchKernelGGL(cvt_kernel, dim3(M_ * D_ / 2048, 2), dim3(256), 0, stream, ca);

  TransArgs ta;
  const int widx[6] = {2, 4, 6, 10, 12, 8};
  bf16_t* wdst[6] = {wtq, wtk, wtv, wts, wtsh, wto};
  for (int i = 0; i < 6; ++i) { ta.src[i] = d_in[widx[i]]; ta.srcIdx[i] = widx[i]; ta.dst[i] = wdst[i]; }
  ta.flags = flags;
  hipLaunchKernelGGL(transpose_kernel, dim3(8, 8, 6), dim3(256), 0, stream, ta);

  // g1a: Q, scale, shift projections — 1536 blocks x 512 thr, 3-slot pipeline
  GemmBatch g1;
  g1.A[0] = m1b; g1.A[1] = m2b; g1.A[2] = m2b;
  g1.Bt[0] = wtq; g1.Bt[1] = wts; g1.Bt[2] = wtsh;
  g1.bias[0] = d_in[3];  g1.bIdx[0] = 3;
  g1.bias[1] = d_in[11]; g1.bIdx[1] = 11;
  g1.bias[2] = d_in[13]; g1.bIdx[2] = 13;
  g1.C[0] = q_buf; g1.cIdx[0] = -1;
  g1.C[1] = stmp;  g1.cIdx[1] = -1;
  g1.C[2] = shtmp; g1.cIdx[2] = -1;
  g1.flags = flags;
  hipLaunchKernelGGL(gemm_bt_kernel, dim3(M_ / 128, 8, 3), dim3(512), 0, stream, g1);

  // g1b: K, V projections + fused modulation — 1024 blocks x 512 thr
  GemmModArgs gm;
  gm.A = m2b;
  gm.Bt[0] = wtk; gm.Bt[1] = wtv;
  gm.bias[0] = d_in[5]; gm.bIdx[0] = 5;
  gm.bias[1] = d_in[7]; gm.bIdx[1] = 7;
  gm.Sc = stmp; gm.Sh = shtmp;
  gm.Kmod = kmod; gm.VtT = vtb;
  gm.flags = flags;
  hipLaunchKernelGGL(gemm_mod_kernel, dim3(M_ / 128, 8, 2), dim3(512), 0, stream, gm);

  // attn: 512 blocks x 512 threads (v12, proven), 3-slot pipeline, vmcnt(2)
  hipLaunchKernelGGL(attn_kernel, dim3(512), dim3(512), 0, stream,
                     q_buf, kmod, vtb, attn_b);

  // g2: out = attn @ Wo^T + bo — 512 blocks x 512 thr
  GemmBatch g2;
  for (int i = 0; i < 3; ++i) {
    g2.A[i] = attn_b;
    g2.Bt[i] = wto;
    g2.bias[i] = d_in[9]; g2.bIdx[i] = 9;
    g2.C[i] = d_out; g2.cIdx[i] = 0;
  }
  g2.flags = flags;
  hipLaunchKernelGGL(gemm_bt_kernel, dim3(M_ / 128, 8, 1), dim3(512), 0, stream, g2);
}

// Round 7
// 201.791 us; speedup vs baseline: 1.1197x; 1.0669x over previous
//
#include <hip/hip_runtime.h>
#include <hip/hip_bf16.h>
#include <cstdint>
#include <cstddef>

typedef __bf16 bf16_t;
typedef __bf16 bf16x8 __attribute__((ext_vector_type(8)));
typedef __bf16 bf16x4 __attribute__((ext_vector_type(4)));
typedef float f32x4 __attribute__((ext_vector_type(4)));

#define DEVINL static __device__ __forceinline__

constexpr int B_ = 4, S_ = 2048, D_ = 512, H_ = 8, HD_ = 64;
constexpr int M_ = B_ * S_;   // 8192
constexpr int NIN = 14;

DEVINL bf16x8 load8g(const bf16_t* p) { return *reinterpret_cast<const bf16x8*>(p); }

// XOR-swizzle: permute 16B-chunk index by row&7 within each aligned 64-elem group.
DEVINL int swcol(int col, int row) {
  return (col & ~63) | ((((col >> 3) ^ row) & 7) << 3) | (col & 7);
}

// K-specific swizzle keyed on row bits {0,1,3} (attn kf reads permuted rows).
DEVINL int pK(int row) { return (row & 3) | (((row >> 3) & 1) << 2); }
DEVINL int swcolK(int col, int row) {
  return (col & ~63) | ((((col >> 3) ^ pK(row)) & 7) << 3) | (col & 7);
}

// async global->LDS, 16 B/lane. LDS dest is wave-uniform base + lane*16 (m104/m108).
DEVINL void gl2lds(const bf16_t* g, bf16_t* l) {
  __builtin_amdgcn_global_load_lds(
      (const __attribute__((address_space(1))) void*)g,
      (__attribute__((address_space(3))) void*)l, 16, 0, 0);
}

DEVINL void stage16(bf16_t* dst, const void* src, size_t off, bool f32) {
  if (f32) {
    const float* p = (const float*)src + off;
    bf16x8 v0, v1;
#pragma unroll
    for (int j = 0; j < 8; ++j) { v0[j] = (bf16_t)p[j]; v1[j] = (bf16_t)p[8 + j]; }
    *reinterpret_cast<bf16x8*>(dst)     = v0;
    *reinterpret_cast<bf16x8*>(dst + 8) = v1;
  } else {
    const bf16_t* p = (const bf16_t*)src + off;
    *reinterpret_cast<bf16x8*>(dst)     = load8g(p);
    *reinterpret_cast<bf16x8*>(dst + 8) = load8g(p + 8);
  }
}

DEVINL float readf(const void* p, size_t i, bool f32) {
  return f32 ? ((const float*)p)[i] : (float)((const bf16_t*)p)[i];
}

// ---------------- dtype detect: flags[i]=1 iff input i is float32 ----------------
struct DetectArgs { const uint16_t* p[NIN]; int n[NIN]; int* flags; };

__global__ __launch_bounds__(64) void detect_kernel(DetectArgs a) {
  const int z = blockIdx.x;
  const uint16_t* p = a.p[z];
  const int n = a.n[z];
  const int t = threadIdx.x;
  int cnt = 0;
  for (int i = t; i < n; i += 64) {
    const int e = (p[i] >> 7) & 0xFF;
    cnt += (e >= 200);
  }
#pragma unroll
  for (int off = 32; off > 0; off >>= 1) cnt += __shfl_down(cnt, off, 64);
  if (t == 0) a.flags[z] = (cnt > 16) ? 1 : 0;
}

// -------- cvt: mod features -> packed bf16, SWIZZLED layout (gl2lds consumer) --------
struct CvtArgs { const void* src[2]; bf16_t* dst[2]; int idx[2]; const int* flags; };

__global__ __launch_bounds__(256) void cvt_kernel(CvtArgs a) {
  const int z = blockIdx.y;
  const bool f32 = a.flags[a.idx[z]] != 0;
  const size_t i = ((size_t)blockIdx.x * 256 + threadIdx.x) * 8;
  const int row = (int)(i >> 9);
  const int col = (int)(i & 511);
  bf16_t* dst = a.dst[z] + (size_t)row * 512 + swcol(col, row);
  if (f32) {
    const float* p = (const float*)a.src[z] + i;
    bf16x8 v;
#pragma unroll
    for (int j = 0; j < 8; ++j) v[j] = (bf16_t)p[j];
    *reinterpret_cast<bf16x8*>(dst) = v;
  } else {
    *reinterpret_cast<bf16x8*>(dst) = load8g((const bf16_t*)a.src[z] + i);
  }
}

// -------- weight transpose: WT[n][k] = W[k][n], SWIZZLED output (gl2lds consumer) --------
struct TransArgs { const void* src[6]; int srcIdx[6]; bf16_t* dst[6]; const int* flags; };

__global__ __launch_bounds__(256) void transpose_kernel(TransArgs a) {
  __shared__ bf16_t tile[64][80];
  const int w = blockIdx.z;
  const void* src = a.src[w];
  const bool f32 = a.flags[a.srcIdx[w]] != 0;
  bf16_t* dst = a.dst[w];
  const int k0 = blockIdx.x * 64, n0 = blockIdx.y * 64;
  const int t = threadIdx.x;
  const int r = t >> 2, c0 = (t & 3) * 16;
  stage16(&tile[r][c0], src, (size_t)(k0 + r) * 512 + n0 + c0, f32);
  __syncthreads();
  const int orow = n0 + r;
  bf16_t* o = dst + (size_t)orow * 512;
#pragma unroll
  for (int half = 0; half < 2; ++half) {
    bf16x8 ov;
#pragma unroll
    for (int j = 0; j < 8; ++j) ov[j] = tile[c0 + half * 8 + j][r];
    *reinterpret_cast<bf16x8*>(o + swcol(k0 + c0 + half * 8, orow)) = ov;
  }
}

// ---- GEMM + bias, 128x64 tile, BK=64, 512 thr / 8 waves (16-row strip per wave).
// 3-slot LDS ring, fused {s_waitcnt vmcnt(3); s_barrier}, prefetch distance 2. ----
struct GemmBatch {
  const bf16_t* A[3];
  const bf16_t* Bt[3];
  const void* bias[3]; int bIdx[3];
  void* C[3];          int cIdx[3];
  const int* flags;
};

__global__ __launch_bounds__(512) void gemm_bt_kernel(GemmBatch args) {
  constexpr int K = 512, N = 512;
  __shared__ bf16_t As[3][128][64];   // 48 KB
  __shared__ bf16_t Bs[3][64][64];    // 24 KB
  const int z = blockIdx.z;
  const bf16_t* Ag  = args.A[z];
  const bf16_t* Btg = args.Bt[z];
  const int m0 = blockIdx.x * 128, n0 = blockIdx.y * 64;
  const int t = threadIdx.x, lane = t & 63, wave = t >> 6;   // wave 0..7
  const int l16 = lane & 15, quad = lane >> 4;
  const int wm = wave * 16;
  const int lr = lane >> 3, lc = (lane & 7) * 8;   // 8 rows x 128 B per gl2lds

  auto stage = [&](int slot, int k0) {
#pragma unroll
    for (int s = 0; s < 2; ++s) {
      const int r = wm + s * 8;
      gl2lds(Ag + (size_t)(m0 + r + lr) * K + k0 + lc, &As[slot][r][0]);
    }
    gl2lds(Btg + (size_t)(n0 + wave * 8 + lr) * K + k0 + lc, &Bs[slot][wave * 8][0]);
  };

  f32x4 acc[4] = {};

  stage(0, 0);
  stage(1, 64);

  constexpr int NT = K / 64;   // 8
  int cur = 0;
  for (int kt = 0; kt < NT - 1; ++kt) {
    asm volatile("s_waitcnt vmcnt(3)\n\ts_barrier" ::: "memory");
    __builtin_amdgcn_sched_barrier(0);
    if (kt + 2 < NT) {
      const int slot2 = cur == 0 ? 2 : cur - 1;
      stage(slot2, (kt + 2) * 64);
    }
#pragma unroll
    for (int ks = 0; ks < 2; ++ks) {
      const int sw = swcol(ks * 32 + quad * 8, l16);
      bf16x8 af = *reinterpret_cast<const bf16x8*>(&As[cur][wm + l16][sw]);
      bf16x8 bfr[4];
#pragma unroll
      for (int j = 0; j < 4; ++j)
        bfr[j] = *reinterpret_cast<const bf16x8*>(&Bs[cur][j * 16 + l16][sw]);
#pragma unroll
      for (int j = 0; j < 4; ++j)
        acc[j] = __builtin_amdgcn_mfma_f32_16x16x32_bf16(af, bfr[j], acc[j], 0, 0, 0);
    }
    cur = (cur == 2) ? 0 : cur + 1;
  }
  asm volatile("s_waitcnt vmcnt(0)\n\ts_barrier" ::: "memory");
  __builtin_amdgcn_sched_barrier(0);
#pragma unroll
  for (int ks = 0; ks < 2; ++ks) {
    const int sw = swcol(ks * 32 + quad * 8, l16);
    bf16x8 af = *reinterpret_cast<const bf16x8*>(&As[cur][wm + l16][sw]);
    bf16x8 bfr[4];
#pragma unroll
    for (int j = 0; j < 4; ++j)
      bfr[j] = *reinterpret_cast<const bf16x8*>(&Bs[cur][j * 16 + l16][sw]);
#pragma unroll
    for (int j = 0; j < 4; ++j)
      acc[j] = __builtin_amdgcn_mfma_f32_16x16x32_bf16(af, bfr[j], acc[j], 0, 0, 0);
  }

  // epilogue (flags read only now -> no VMEM during loop besides gl2lds)
  const void* biag = args.bias[z];
  void* Cg         = args.C[z];
  const bool bf32 = args.bIdx[z] >= 0 && args.flags[args.bIdx[z]];
  const bool cf32 = args.cIdx[z] >= 0 && args.flags[args.cIdx[z]];
#pragma unroll
  for (int j = 0; j < 4; ++j) {
    const int col = n0 + j * 16 + l16;
    const float bv = readf(biag, col, bf32);
    const int rowb = m0 + wm + quad * 4;
#pragma unroll
    for (int r = 0; r < 4; ++r) {
      const size_t idx = (size_t)(rowb + r) * N + col;
      const float v = acc[j][r] + bv;
      if (cf32) ((float*)Cg)[idx] = v;
      else      ((bf16_t*)Cg)[idx] = (bf16_t)v;
    }
  }
}

// ---- FUSED K/V/scale/shift projection + modulation. One block = one 128x64 output
// tile of ALL FOUR matrices (shared A staging: 4x fewer A passes), modulation applied
// in-register (stmp/shtmp buffers and their 32 MB round-trip deleted; scale/shift kept
// in f32 -> one fewer rounding). 512 thr / 8 waves split 2m x 4n (B reads not 8-way
// duplicated). 3-slot ring (144 KB LDS <= 160), dist-2, 6 gl2lds/wave/tile -> vmcnt(6).
struct KsvArgs {
  const bf16_t* A;          // m2b (swizzled)
  const bf16_t* Bt[4];      // wtk, wtv, wts, wtsh (swizzled)
  const void* bias[4]; int bIdx[4];   // bk, bv, bs, bsh
  bf16_t* Kmod;             // [M,512] swcolK (attn kf consumer)
  bf16_t* VtT;              // [B][H][HD][S] swcol
  const int* flags;
};

__global__ __launch_bounds__(512) void ksv_kernel(KsvArgs args) {
  constexpr int K = 512;
  __shared__ bf16_t As[3][128][64];       // 48 KB
  __shared__ bf16_t Bs[3][4][64][64];     // 96 KB
  const int m0 = blockIdx.x * 128, n0 = blockIdx.y * 64;
  const int t = threadIdx.x, lane = t & 63, wave = t >> 6;   // 0..7
  const int l16 = lane & 15, quad = lane >> 4;
  const int wm = (wave >> 2) * 64;        // 0 or 64
  const int wn = (wave & 3) * 16;         // 0,16,32,48
  const int lr = lane >> 3, lc = (lane & 7) * 8;

  auto stage = [&](int slot, int k0) {
#pragma unroll
    for (int s = 0; s < 2; ++s) {          // A: 16 gl2lds / 8 waves = 2
      const int r = wave * 16 + s * 8;
      gl2lds(args.A + (size_t)(m0 + r + lr) * K + k0 + lc, &As[slot][r][0]);
    }
    const int mat = wave >> 1;             // B: 32 gl2lds / 8 waves = 4
    const int rb = (wave & 1) * 32;
#pragma unroll
    for (int s = 0; s < 4; ++s) {
      const int r = rb + s * 8;
      gl2lds(args.Bt[mat] + (size_t)(n0 + r + lr) * K + k0 + lc, &Bs[slot][mat][r][0]);
    }
  };

  f32x4 acc[4][4] = {};   // [mat: K,V,S,Sh][mi]

  stage(0, 0);
  stage(1, 64);

  constexpr int NT = K / 64;   // 8
  int cur = 0;
  for (int kt = 0; kt < NT - 1; ++kt) {
    asm volatile("s_waitcnt vmcnt(6)\n\ts_barrier" ::: "memory");
    __builtin_amdgcn_sched_barrier(0);
    if (kt + 2 < NT) {
      const int slot2 = cur == 0 ? 2 : cur - 1;
      stage(slot2, (kt + 2) * 64);
    }
#pragma unroll
    for (int ks = 0; ks < 2; ++ks) {
      const int sw = swcol(ks * 32 + quad * 8, l16);
      bf16x8 af[4], bfr[4];
#pragma unroll
      for (int mi = 0; mi < 4; ++mi)
        af[mi] = *reinterpret_cast<const bf16x8*>(&As[cur][wm + mi * 16 + l16][sw]);
#pragma unroll
      for (int mat = 0; mat < 4; ++mat)
        bfr[mat] = *reinterpret_cast<const bf16x8*>(&Bs[cur][mat][wn + l16][sw]);
#pragma unroll
      for (int mat = 0; mat < 4; ++mat)
#pragma unroll
        for (int mi = 0; mi < 4; ++mi)
          acc[mat][mi] = __builtin_amdgcn_mfma_f32_16x16x32_bf16(af[mi], bfr[mat], acc[mat][mi], 0, 0, 0);
    }
    cur = (cur == 2) ? 0 : cur + 1;
  }
  asm volatile("s_waitcnt vmcnt(0)\n\ts_barrier" ::: "memory");
  __builtin_amdgcn_sched_barrier(0);
#pragma unroll
  for (int ks = 0; ks < 2; ++ks) {
    const int sw = swcol(ks * 32 + quad * 8, l16);
    bf16x8 af[4], bfr[4];
#pragma unroll
    for (int mi = 0; mi < 4; ++mi)
      af[mi] = *reinterpret_cast<const bf16x8*>(&As[cur][wm + mi * 16 + l16][sw]);
#pragma unroll
    for (int mat = 0; mat < 4; ++mat)
      bfr[mat] = *reinterpret_cast<const bf16x8*>(&Bs[cur][mat][wn + l16][sw]);
#pragma unroll
    for (int mat = 0; mat < 4; ++mat)
#pragma unroll
      for (int mi = 0; mi < 4; ++mi)
        acc[mat][mi] = __builtin_amdgcn_mfma_f32_16x16x32_bf16(af[mi], bfr[mat], acc[mat][mi], 0, 0, 0);
  }

  // fused epilogue: s = S+bs, sh = Sh+bsh (f32, unrounded); K' = (K+bk)*s+sh; V' likewise.
  const int col = n0 + wn + l16;
  const float bk  = readf(args.bias[0], col, args.bIdx[0] >= 0 && args.flags[args.bIdx[0]]);
  const float bv  = readf(args.bias[1], col, args.bIdx[1] >= 0 && args.flags[args.bIdx[1]]);
  const float bs  = readf(args.bias[2], col, args.bIdx[2] >= 0 && args.flags[args.bIdx[2]]);
  const float bsh = readf(args.bias[3], col, args.bIdx[3] >= 0 && args.flags[args.bIdx[3]]);
  const int hh = col >> 6, dd = col & 63;
#pragma unroll
  for (int mi = 0; mi < 4; ++mi) {
    const int rowb = m0 + wm + mi * 16 + quad * 4;
    bf16x4 vpack;
#pragma unroll
    for (int r = 0; r < 4; ++r) {
      const int row = rowb + r;
      const float s  = acc[2][mi][r] + bs;
      const float sh = acc[3][mi][r] + bsh;
      const float kk = fmaf(acc[0][mi][r] + bk, s, sh);
      const float vv = fmaf(acc[1][mi][r] + bv, s, sh);
      args.Kmod[(size_t)row * 512 + swcolK(col, row)] = (bf16_t)kk;
      vpack[r] = (bf16_t)vv;
    }
    const int bb = rowb >> 11;      // batch (tile never crosses batch)
    const int ss = rowb & 2047;     // seq (multiple of 4)
    *reinterpret_cast<bf16x4*>(
        args.VtT + (((size_t)(bb * H_ + hh)) * HD_ + dd) * S_ + swcol(ss, dd)) = vpack;
  }
}

// ---- flash attention v12 (proven): 512 blocks x 512 thr (8 waves x 16 q).
// 3-slot K/V LDS ring (48 KB), fused {s_waitcnt vmcnt(2); s_barrier}, prefetch dist 2. ----
__global__ __launch_bounds__(512) void attn_kernel(const bf16_t* Q, const bf16_t* Kb,
                                                   const bf16_t* Vt, bf16_t* O) {
  __shared__ bf16_t Ks[3][64][64];    // 24 KB (gl2lds dest, swcolK data)
  __shared__ bf16_t Vs[3][64][64];    // 24 KB (swcol data)
  const int i = blockIdx.x;
  const int xcd = i & 7, g = i >> 3;     // g in 0..63
  const int slice = xcd * 4 + (g & 3);   // (b,h): 4 slices per XCD
  const int qt = g >> 2;                 // 0..15
  const int b = slice >> 3, h = slice & 7;
  const int t = threadIdx.x, wave = t >> 6, lane = t & 63;   // wave 0..7
  const int l16 = lane & 15, quad = lane >> 4;
  const int q0 = qt * 128 + wave * 16;   // 16 q-rows per wave
  const int lr = lane >> 3, lc = (lane & 7) * 8;

  bf16x8 ones;
#pragma unroll
  for (int j = 0; j < 8; ++j) ones[j] = (bf16_t)1.0f;

  bf16x8 qf[2];   // q_buf NORMAL layout; [dc]
  {
    const size_t qrow = ((size_t)b * S_ + q0 + l16) * D_ + h * HD_;
    qf[0] = load8g(Q + qrow + quad * 8);
    qf[1] = load8g(Q + qrow + 32 + quad * 8);
  }

  f32x4 oacc[4] = {};
  f32x4 lacc = {};

  const size_t kbase = (size_t)b * S_ * D_ + h * HD_;
  const size_t vbase = ((size_t)(b * H_ + h)) * HD_ * S_;

  const int rbase = ((l16 >> 2) << 3) | (l16 & 3);
  int koff[2][4];   // [dc][j]
#pragma unroll
  for (int j = 0; j < 4; ++j) {
    const int rho = rbase + (j >> 1) * 32 + (j & 1) * 4;
#pragma unroll
    for (int dc = 0; dc < 2; ++dc)
      koff[dc][j] = rho * 64 + swcolK(dc * 32 + quad * 8, rho);
  }
  const int voff[2] = { swcol(quad * 8, l16), swcol(32 + quad * 8, l16) };

  auto stage = [&](int slot, int k0) {
    const int r = wave * 8;
    gl2lds(Kb + kbase + (size_t)(k0 + r + lr) * D_ + lc, &Ks[slot][r][0]);
    gl2lds(Vt + vbase + (size_t)(r + lr) * S_ + k0 + lc, &Vs[slot][r][0]);
  };

  constexpr float CE = 0.18033688011112042f;  // 0.125 * log2(e)

  auto compute = [&](int cur) {
    f32x4 sacc[4] = {};
    const bf16_t* ksbase = &Ks[cur][0][0];
#pragma unroll
    for (int dc = 0; dc < 2; ++dc) {
      bf16x8 kf[4];
#pragma unroll
      for (int j = 0; j < 4; ++j)
        kf[j] = *reinterpret_cast<const bf16x8*>(ksbase + koff[dc][j]);
#pragma unroll
      for (int j = 0; j < 4; ++j)
        sacc[j] = __builtin_amdgcn_mfma_f32_16x16x32_bf16(kf[j], qf[dc], sacc[j], 0, 0, 0);
    }
#pragma unroll
    for (int kc = 0; kc < 2; ++kc) {
      bf16x8 vf[4];
#pragma unroll
      for (int dj = 0; dj < 4; ++dj)
        vf[dj] = *reinterpret_cast<const bf16x8*>(&Vs[cur][dj * 16 + l16][voff[kc]]);
      bf16x8 bp;
#pragma unroll
      for (int r = 0; r < 4; ++r) {
        bp[r]     = (bf16_t)__builtin_amdgcn_exp2f(fminf(sacc[kc * 2][r]     * CE, 57.5f));
        bp[4 + r] = (bf16_t)__builtin_amdgcn_exp2f(fminf(sacc[kc * 2 + 1][r] * CE, 57.5f));
      }
#pragma unroll
      for (int dj = 0; dj < 4; ++dj)
        oacc[dj] = __builtin_amdgcn_mfma_f32_16x16x32_bf16(vf[dj], bp, oacc[dj], 0, 0, 0);
      lacc = __builtin_amdgcn_mfma_f32_16x16x32_bf16(ones, bp, lacc, 0, 0, 0);
    }
  };

  // drain Q loads once so the loop's vmcnt ledger counts only gl2lds ops
  asm volatile("s_waitcnt vmcnt(0)" ::: "memory");
  stage(0, 0);
  stage(1, 64);

  constexpr int NT = S_ / 64;   // 32
  int cur = 0;
  for (int kt = 0; kt < NT - 1; ++kt) {
    asm volatile("s_waitcnt vmcnt(2)\n\ts_barrier" ::: "memory");
    __builtin_amdgcn_sched_barrier(0);
    if (kt + 2 < NT) {
      const int slot2 = cur == 0 ? 2 : cur - 1;   // (kt+2)%3, freed at barrier above
      stage(slot2, (kt + 2) * 64);
    }
    compute(cur);
    cur = (cur == 2) ? 0 : cur + 1;
  }
  asm volatile("s_waitcnt vmcnt(0)\n\ts_barrier" ::: "memory");
  __builtin_amdgcn_sched_barrier(0);
  compute(cur);

  // ---- epilogue: O[q][d] = O^T[d][q] / l[q]; packed 8B stores, SWIZZLED (feeds g2) ----
  {
    const float linv = 1.0f / fmaxf(lacc[0], 1e-30f);
    const int q = q0 + l16;
    const size_t orow = ((size_t)b * S_ + q) * D_ + h * HD_;
#pragma unroll
    for (int dj = 0; dj < 4; ++dj) {
      bf16x4 pack;
#pragma unroll
      for (int r = 0; r < 4; ++r) pack[r] = (bf16_t)(oacc[dj][r] * linv);
      *reinterpret_cast<bf16x4*>(&O[orow + swcol(dj * 16 + quad * 4, q)]) = pack;
    }
  }
}

// ---------------- host launcher ----------------
extern "C" void kernel_launch(void* const* d_in, const int* in_sizes, int n_in,
                              void* d_out, int out_size, void* d_ws, size_t ws_size,
                              hipStream_t stream) {
  (void)n_in; (void)out_size; (void)ws_size;

  char* ws = (char*)d_ws;
  auto alloc = [&](size_t bytes) -> char* {
    char* p = ws; ws += (bytes + 255) & ~(size_t)255; return p;
  };
  int* flags = (int*)alloc(64 * sizeof(int));
  const size_t wbytes = (size_t)512 * 512 * sizeof(bf16_t);
  const size_t fbytes = (size_t)M_ * D_ * sizeof(bf16_t);
  bf16_t* wt    = (bf16_t*)alloc(6 * wbytes);  // 3 MB (swizzled)
  bf16_t* m1b   = (bf16_t*)alloc(fbytes);      // 8 MB mod1 bf16 swizzled; vtb alias after qproj
  bf16_t* m2b   = (bf16_t*)alloc(fbytes);      // 8 MB mod2 bf16 swizzled
  bf16_t* q_buf = (bf16_t*)alloc(fbytes);      // 8 MB normal
  bf16_t* atmp  = (bf16_t*)alloc(fbytes);      // 8 MB attn output (swizzled)
  bf16_t* kmod  = (bf16_t*)alloc(fbytes);      // 8 MB swizzled (swcolK)
  bf16_t* vtb    = m1b;    // alias: m1b dead after qproj
  bf16_t* attn_b = atmp;

  bf16_t* wtq  = wt + 0 * 512 * 512;
  bf16_t* wtk  = wt + 1 * 512 * 512;
  bf16_t* wtv  = wt + 2 * 512 * 512;
  bf16_t* wts  = wt + 3 * 512 * 512;
  bf16_t* wtsh = wt + 4 * 512 * 512;
  bf16_t* wto  = wt + 5 * 512 * 512;

  DetectArgs da;
  for (int i = 0; i < NIN; ++i) {
    da.p[i] = (const uint16_t*)d_in[i];
    da.n[i] = in_sizes[i] < 2048 ? in_sizes[i] : 2048;
  }
  da.flags = flags;
  hipLaunchKernelGGL(detect_kernel, dim3(NIN), dim3(64), 0, stream, da);

  CvtArgs ca;
  ca.src[0] = d_in[0]; ca.dst[0] = m1b; ca.idx[0] = 0;
  ca.src[1] = d_in[1]; ca.dst[1] = m2b; ca.idx[1] = 1;
  ca.flags = flags;
  hipLaunchKernelGGL(cvt_kernel, dim3(M_ * D_ / 2048, 2), dim3(256), 0, stream, ca);

  TransArgs ta;
  const int widx[6] = {2, 4, 6, 10, 12, 8};
  bf16_t* wdst[6] = {wtq, wtk, wtv, wts, wtsh, wto};
  for (int i = 0; i < 6; ++i) { ta.src[i] = d_in[widx[i]]; ta.srcIdx[i] = widx[i]; ta.dst[i] = wdst[i]; }
  ta.flags = flags;
  hipLaunchKernelGGL(transpose_kernel, dim3(8, 8, 6), dim3(256), 0, stream, ta);

  // qproj: Q projection only — 512 blocks x 512 thr, 3-slot pipeline
  GemmBatch g1;
  g1.A[0] = m1b;  g1.A[1] = m1b;  g1.A[2] = m1b;
  g1.Bt[0] = wtq; g1.Bt[1] = wtq; g1.Bt[2] = wtq;
  g1.bias[0] = d_in[3];  g1.bIdx[0] = 3;
  g1.bias[1] = d_in[3];  g1.bIdx[1] = 3;
  g1.bias[2] = d_in[3];  g1.bIdx[2] = 3;
  g1.C[0] = q_buf; g1.cIdx[0] = -1;
  g1.C[1] = q_buf; g1.cIdx[1] = -1;
  g1.C[2] = q_buf; g1.cIdx[2] = -1;
  g1.flags = flags;
  hipLaunchKernelGGL(gemm_bt_kernel, dim3(M_ / 128, 8, 1), dim3(512), 0, stream, g1);

  // ksv: fused K/V/scale/shift projections + in-register modulation — 512 blocks x 512 thr
  KsvArgs kv;
  kv.A = m2b;
  kv.Bt[0] = wtk; kv.Bt[1] = wtv; kv.Bt[2] = wts; kv.Bt[3] = wtsh;
  kv.bias[0] = d_in[5];  kv.bIdx[0] = 5;
  kv.bias[1] = d_in[7];  kv.bIdx[1] = 7;
  kv.bias[2] = d_in[11]; kv.bIdx[2] = 11;
  kv.bias[3] = d_in[13]; kv.bIdx[3] = 13;
  kv.Kmod = kmod; kv.VtT = vtb;
  kv.flags = flags;
  hipLaunchKernelGGL(ksv_kernel, dim3(M_ / 128, 8), dim3(512), 0, stream, kv);

  // attn: 512 blocks x 512 threads (v12), 3-slot pipeline, vmcnt(2)
  hipLaunchKernelGGL(attn_kernel, dim3(512), dim3(512), 0, stream,
                     q_buf, kmod, vtb, attn_b);

  // g2: out = attn @ Wo^T + bo — 512 blocks x 512 thr
  GemmBatch g2;
  for (int i = 0; i < 3; ++i) {
    g2.A[i] = attn_b;
    g2.Bt[i] = wto;
    g2.bias[i] = d_in[9]; g2.bIdx[i] = 9;
    g2.C[i] = d_out; g2.cIdx[i] = 0;
  }
  g2.flags = flags;
  hipLaunchKernelGGL(gemm_bt_kernel, dim3(M_ / 128, 8, 1), dim3(512), 0, stream, g2);
}

// Round 8
// 194.755 us; speedup vs baseline: 1.1602x; 1.0361x over previous
//
#include <hip/hip_runtime.h>
#include <hip/hip_bf16.h>
#include <cstdint>
#include <cstddef>

typedef __bf16 bf16_t;
typedef __bf16 bf16x8 __attribute__((ext_vector_type(8)));
typedef __bf16 bf16x4 __attribute__((ext_vector_type(4)));
typedef float f32x4 __attribute__((ext_vector_type(4)));

#define DEVINL static __device__ __forceinline__

constexpr int B_ = 4, S_ = 2048, D_ = 512, H_ = 8, HD_ = 64;
constexpr int M_ = B_ * S_;   // 8192
constexpr int NIN = 14;

DEVINL bf16x8 load8g(const bf16_t* p) { return *reinterpret_cast<const bf16x8*>(p); }

// XOR-swizzle: permute 16B-chunk index by row&7 within each aligned 64-elem group.
DEVINL int swcol(int col, int row) {
  return (col & ~63) | ((((col >> 3) ^ row) & 7) << 3) | (col & 7);
}

// K-specific swizzle keyed on row bits {0,1,3} (attn kf reads permuted rows).
DEVINL int pK(int row) { return (row & 3) | (((row >> 3) & 1) << 2); }
DEVINL int swcolK(int col, int row) {
  return (col & ~63) | ((((col >> 3) ^ pK(row)) & 7) << 3) | (col & 7);
}

// async global->LDS, 16 B/lane. LDS dest is wave-uniform base + lane*16 (m104/m108).
DEVINL void gl2lds(const bf16_t* g, bf16_t* l) {
  __builtin_amdgcn_global_load_lds(
      (const __attribute__((address_space(1))) void*)g,
      (__attribute__((address_space(3))) void*)l, 16, 0, 0);
}

DEVINL void stage16(bf16_t* dst, const void* src, size_t off, bool f32) {
  if (f32) {
    const float* p = (const float*)src + off;
    bf16x8 v0, v1;
#pragma unroll
    for (int j = 0; j < 8; ++j) { v0[j] = (bf16_t)p[j]; v1[j] = (bf16_t)p[8 + j]; }
    *reinterpret_cast<bf16x8*>(dst)     = v0;
    *reinterpret_cast<bf16x8*>(dst + 8) = v1;
  } else {
    const bf16_t* p = (const bf16_t*)src + off;
    *reinterpret_cast<bf16x8*>(dst)     = load8g(p);
    *reinterpret_cast<bf16x8*>(dst + 8) = load8g(p + 8);
  }
}

DEVINL float readf(const void* p, size_t i, bool f32) {
  return f32 ? ((const float*)p)[i] : (float)((const bf16_t*)p)[i];
}

// ---------------- dtype detect: flags[i]=1 iff input i is float32 ----------------
struct DetectArgs { const uint16_t* p[NIN]; int n[NIN]; int* flags; };

__global__ __launch_bounds__(64) void detect_kernel(DetectArgs a) {
  const int z = blockIdx.x;
  const uint16_t* p = a.p[z];
  const int n = a.n[z];
  const int t = threadIdx.x;
  int cnt = 0;
  for (int i = t; i < n; i += 64) {
    const int e = (p[i] >> 7) & 0xFF;
    cnt += (e >= 200);
  }
#pragma unroll
  for (int off = 32; off > 0; off >>= 1) cnt += __shfl_down(cnt, off, 64);
  if (t == 0) a.flags[z] = (cnt > 16) ? 1 : 0;
}

// -------- prep: cvt (mod feats -> bf16 swizzled) + weight transpose, ONE dispatch --------
struct PrepArgs {
  const void* csrc[2]; bf16_t* cdst[2]; int cidx[2];
  const void* wsrc[6]; int wIdx[6]; bf16_t* wdst[6];
  const int* flags;
};

__global__ __launch_bounds__(256) void prep_kernel(PrepArgs a) {
  __shared__ bf16_t tile[64][80];
  const int bid = blockIdx.x;
  if (bid < 4096) {
    // ---- cvt part: 2 mats x 2048 blocks ----
    const int z = bid >> 11;
    const int bx = bid & 2047;
    const bool f32 = a.flags[a.cidx[z]] != 0;
    const size_t i = ((size_t)bx * 256 + threadIdx.x) * 8;
    const int row = (int)(i >> 9);
    const int col = (int)(i & 511);
    bf16_t* dst = a.cdst[z] + (size_t)row * 512 + swcol(col, row);
    if (f32) {
      const float* p = (const float*)a.csrc[z] + i;
      bf16x8 v;
#pragma unroll
      for (int j = 0; j < 8; ++j) v[j] = (bf16_t)p[j];
      *reinterpret_cast<bf16x8*>(dst) = v;
    } else {
      *reinterpret_cast<bf16x8*>(dst) = load8g((const bf16_t*)a.csrc[z] + i);
    }
  } else {
    // ---- transpose part: 6 weights x 64 tiles ----
    const int rem = bid - 4096;
    const int w = rem >> 6;
    const int r6 = rem & 63;
    const int k0 = (r6 & 7) * 64, n0 = (r6 >> 3) * 64;
    const void* src = a.wsrc[w];
    const bool f32 = a.flags[a.wIdx[w]] != 0;
    bf16_t* dst = a.wdst[w];
    const int t = threadIdx.x;
    const int r = t >> 2, c0 = (t & 3) * 16;
    stage16(&tile[r][c0], src, (size_t)(k0 + r) * 512 + n0 + c0, f32);
    __syncthreads();
    const int orow = n0 + r;
    bf16_t* o = dst + (size_t)orow * 512;
#pragma unroll
    for (int half = 0; half < 2; ++half) {
      bf16x8 ov;
#pragma unroll
      for (int j = 0; j < 8; ++j) ov[j] = tile[c0 + half * 8 + j][r];
      *reinterpret_cast<bf16x8*>(o + swcol(k0 + c0 + half * 8, orow)) = ov;
    }
  }
}

// ---- GEMM + bias, 128x64 tile, BK=64, 512 thr / 8 waves (16-row strip per wave).
// 3-slot LDS ring, fused {s_waitcnt vmcnt(3); s_barrier}, prefetch distance 2. ----
struct GemmBatch {
  const bf16_t* A[3];
  const bf16_t* Bt[3];
  const void* bias[3]; int bIdx[3];
  void* C[3];          int cIdx[3];
  const int* flags;
};

__global__ __launch_bounds__(512) void gemm_bt_kernel(GemmBatch args) {
  constexpr int K = 512, N = 512;
  __shared__ bf16_t As[3][128][64];   // 48 KB
  __shared__ bf16_t Bs[3][64][64];    // 24 KB
  const int z = blockIdx.z;
  const bf16_t* Ag  = args.A[z];
  const bf16_t* Btg = args.Bt[z];
  const int m0 = blockIdx.x * 128, n0 = blockIdx.y * 64;
  const int t = threadIdx.x, lane = t & 63, wave = t >> 6;   // wave 0..7
  const int l16 = lane & 15, quad = lane >> 4;
  const int wm = wave * 16;
  const int lr = lane >> 3, lc = (lane & 7) * 8;   // 8 rows x 128 B per gl2lds

  auto stage = [&](int slot, int k0) {
#pragma unroll
    for (int s = 0; s < 2; ++s) {
      const int r = wm + s * 8;
      gl2lds(Ag + (size_t)(m0 + r + lr) * K + k0 + lc, &As[slot][r][0]);
    }
    gl2lds(Btg + (size_t)(n0 + wave * 8 + lr) * K + k0 + lc, &Bs[slot][wave * 8][0]);
  };

  f32x4 acc[4] = {};

  stage(0, 0);
  stage(1, 64);

  constexpr int NT = K / 64;   // 8
  int cur = 0;
  for (int kt = 0; kt < NT - 1; ++kt) {
    asm volatile("s_waitcnt vmcnt(3)\n\ts_barrier" ::: "memory");
    __builtin_amdgcn_sched_barrier(0);
    if (kt + 2 < NT) {
      const int slot2 = cur == 0 ? 2 : cur - 1;
      stage(slot2, (kt + 2) * 64);
    }
#pragma unroll
    for (int ks = 0; ks < 2; ++ks) {
      const int sw = swcol(ks * 32 + quad * 8, l16);
      bf16x8 af = *reinterpret_cast<const bf16x8*>(&As[cur][wm + l16][sw]);
      bf16x8 bfr[4];
#pragma unroll
      for (int j = 0; j < 4; ++j)
        bfr[j] = *reinterpret_cast<const bf16x8*>(&Bs[cur][j * 16 + l16][sw]);
#pragma unroll
      for (int j = 0; j < 4; ++j)
        acc[j] = __builtin_amdgcn_mfma_f32_16x16x32_bf16(af, bfr[j], acc[j], 0, 0, 0);
    }
    cur = (cur == 2) ? 0 : cur + 1;
  }
  asm volatile("s_waitcnt vmcnt(0)\n\ts_barrier" ::: "memory");
  __builtin_amdgcn_sched_barrier(0);
#pragma unroll
  for (int ks = 0; ks < 2; ++ks) {
    const int sw = swcol(ks * 32 + quad * 8, l16);
    bf16x8 af = *reinterpret_cast<const bf16x8*>(&As[cur][wm + l16][sw]);
    bf16x8 bfr[4];
#pragma unroll
    for (int j = 0; j < 4; ++j)
      bfr[j] = *reinterpret_cast<const bf16x8*>(&Bs[cur][j * 16 + l16][sw]);
#pragma unroll
    for (int j = 0; j < 4; ++j)
      acc[j] = __builtin_amdgcn_mfma_f32_16x16x32_bf16(af, bfr[j], acc[j], 0, 0, 0);
  }

  // epilogue (flags read only now -> no VMEM during loop besides gl2lds)
  const void* biag = args.bias[z];
  void* Cg         = args.C[z];
  const bool bf32 = args.bIdx[z] >= 0 && args.flags[args.bIdx[z]];
  const bool cf32 = args.cIdx[z] >= 0 && args.flags[args.cIdx[z]];
#pragma unroll
  for (int j = 0; j < 4; ++j) {
    const int col = n0 + j * 16 + l16;
    const float bv = readf(biag, col, bf32);
    const int rowb = m0 + wm + quad * 4;
#pragma unroll
    for (int r = 0; r < 4; ++r) {
      const size_t idx = (size_t)(rowb + r) * N + col;
      const float v = acc[j][r] + bv;
      if (cf32) ((float*)Cg)[idx] = v;
      else      ((bf16_t*)Cg)[idx] = (bf16_t)v;
    }
  }
}

// ---- FUSED K/V/scale/shift projection + modulation, v2: 1024 thr / 16 waves.
// Same 144 KB 3-slot ring as round 7 but 16 waves/CU = 4 waves/SIMD (was 2 -> the
// proven-slow latency regime). Wave split 4m x 4n (32x16 per mat); staging uniform
// 3 gl2lds/wave/tile (1 A + 2 B) -> vmcnt(3). Modulation in-register, f32 scale/shift.
struct KsvArgs {
  const bf16_t* A;          // m2b (swizzled)
  const bf16_t* Bt[4];      // wtk, wtv, wts, wtsh (swizzled)
  const void* bias[4]; int bIdx[4];   // bk, bv, bs, bsh
  bf16_t* Kmod;             // [M,512] swcolK (attn kf consumer)
  bf16_t* VtT;              // [B][H][HD][S] swcol
  const int* flags;
};

__global__ __launch_bounds__(1024) void ksv_kernel(KsvArgs args) {
  constexpr int K = 512;
  __shared__ bf16_t As[3][128][64];       // 48 KB
  __shared__ bf16_t Bs[3][4][64][64];     // 96 KB
  const int m0 = blockIdx.x * 128, n0 = blockIdx.y * 64;
  const int t = threadIdx.x, lane = t & 63, wave = t >> 6;   // 0..15
  const int l16 = lane & 15, quad = lane >> 4;
  const int wm = (wave >> 2) * 32;        // 0,32,64,96
  const int wn = (wave & 3) * 16;         // 0,16,32,48
  const int lr = lane >> 3, lc = (lane & 7) * 8;

  auto stage = [&](int slot, int k0) {
    // A: 16 loads, one per wave
    gl2lds(args.A + (size_t)(m0 + wave * 8 + lr) * K + k0 + lc, &As[slot][wave * 8][0]);
    // B: 32 loads, two per wave: mat = wave>>2, rows (wave&3)*16 + {0,8}
    const int mat = wave >> 2;
    const int rb = (wave & 3) * 16;
#pragma unroll
    for (int s = 0; s < 2; ++s) {
      const int r = rb + s * 8;
      gl2lds(args.Bt[mat] + (size_t)(n0 + r + lr) * K + k0 + lc, &Bs[slot][mat][r][0]);
    }
  };

  f32x4 acc[4][2] = {};   // [mat: K,V,S,Sh][mi]

  stage(0, 0);
  stage(1, 64);

  constexpr int NT = K / 64;   // 8
  int cur = 0;
  for (int kt = 0; kt < NT - 1; ++kt) {
    asm volatile("s_waitcnt vmcnt(3)\n\ts_barrier" ::: "memory");
    __builtin_amdgcn_sched_barrier(0);
    if (kt + 2 < NT) {
      const int slot2 = cur == 0 ? 2 : cur - 1;
      stage(slot2, (kt + 2) * 64);
    }
#pragma unroll
    for (int ks = 0; ks < 2; ++ks) {
      const int sw = swcol(ks * 32 + quad * 8, l16);
      bf16x8 af[2], bfr[4];
#pragma unroll
      for (int mi = 0; mi < 2; ++mi)
        af[mi] = *reinterpret_cast<const bf16x8*>(&As[cur][wm + mi * 16 + l16][sw]);
#pragma unroll
      for (int mat = 0; mat < 4; ++mat)
        bfr[mat] = *reinterpret_cast<const bf16x8*>(&Bs[cur][mat][wn + l16][sw]);
#pragma unroll
      for (int mat = 0; mat < 4; ++mat)
#pragma unroll
        for (int mi = 0; mi < 2; ++mi)
          acc[mat][mi] = __builtin_amdgcn_mfma_f32_16x16x32_bf16(af[mi], bfr[mat], acc[mat][mi], 0, 0, 0);
    }
    cur = (cur == 2) ? 0 : cur + 1;
  }
  asm volatile("s_waitcnt vmcnt(0)\n\ts_barrier" ::: "memory");
  __builtin_amdgcn_sched_barrier(0);
#pragma unroll
  for (int ks = 0; ks < 2; ++ks) {
    const int sw = swcol(ks * 32 + quad * 8, l16);
    bf16x8 af[2], bfr[4];
#pragma unroll
    for (int mi = 0; mi < 2; ++mi)
      af[mi] = *reinterpret_cast<const bf16x8*>(&As[cur][wm + mi * 16 + l16][sw]);
#pragma unroll
    for (int mat = 0; mat < 4; ++mat)
      bfr[mat] = *reinterpret_cast<const bf16x8*>(&Bs[cur][mat][wn + l16][sw]);
#pragma unroll
    for (int mat = 0; mat < 4; ++mat)
#pragma unroll
      for (int mi = 0; mi < 2; ++mi)
        acc[mat][mi] = __builtin_amdgcn_mfma_f32_16x16x32_bf16(af[mi], bfr[mat], acc[mat][mi], 0, 0, 0);
  }

  // fused epilogue: s = S+bs, sh = Sh+bsh (f32, unrounded); K' = (K+bk)*s+sh; V' likewise.
  const int col = n0 + wn + l16;
  const float bk  = readf(args.bias[0], col, args.bIdx[0] >= 0 && args.flags[args.bIdx[0]]);
  const float bv  = readf(args.bias[1], col, args.bIdx[1] >= 0 && args.flags[args.bIdx[1]]);
  const float bs  = readf(args.bias[2], col, args.bIdx[2] >= 0 && args.flags[args.bIdx[2]]);
  const float bsh = readf(args.bias[3], col, args.bIdx[3] >= 0 && args.flags[args.bIdx[3]]);
  const int hh = col >> 6, dd = col & 63;
#pragma unroll
  for (int mi = 0; mi < 2; ++mi) {
    const int rowb = m0 + wm + mi * 16 + quad * 4;
    bf16x4 vpack;
#pragma unroll
    for (int r = 0; r < 4; ++r) {
      const int row = rowb + r;
      const float s  = acc[2][mi][r] + bs;
      const float sh = acc[3][mi][r] + bsh;
      const float kk = fmaf(acc[0][mi][r] + bk, s, sh);
      const float vv = fmaf(acc[1][mi][r] + bv, s, sh);
      args.Kmod[(size_t)row * 512 + swcolK(col, row)] = (bf16_t)kk;
      vpack[r] = (bf16_t)vv;
    }
    const int bb = rowb >> 11;      // batch (tile never crosses batch)
    const int ss = rowb & 2047;     // seq (multiple of 4)
    *reinterpret_cast<bf16x4*>(
        args.VtT + (((size_t)(bb * H_ + hh)) * HD_ + dd) * S_ + swcol(ss, dd)) = vpack;
  }
}

// ---- flash attention v12 (proven): 512 blocks x 512 thr (8 waves x 16 q).
// 3-slot K/V LDS ring (48 KB), fused {s_waitcnt vmcnt(2); s_barrier}, prefetch dist 2. ----
__global__ __launch_bounds__(512) void attn_kernel(const bf16_t* Q, const bf16_t* Kb,
                                                   const bf16_t* Vt, bf16_t* O) {
  __shared__ bf16_t Ks[3][64][64];    // 24 KB (gl2lds dest, swcolK data)
  __shared__ bf16_t Vs[3][64][64];    // 24 KB (swcol data)
  const int i = blockIdx.x;
  const int xcd = i & 7, g = i >> 3;     // g in 0..63
  const int slice = xcd * 4 + (g & 3);   // (b,h): 4 slices per XCD
  const int qt = g >> 2;                 // 0..15
  const int b = slice >> 3, h = slice & 7;
  const int t = threadIdx.x, wave = t >> 6, lane = t & 63;   // wave 0..7
  const int l16 = lane & 15, quad = lane >> 4;
  const int q0 = qt * 128 + wave * 16;   // 16 q-rows per wave
  const int lr = lane >> 3, lc = (lane & 7) * 8;

  bf16x8 ones;
#pragma unroll
  for (int j = 0; j < 8; ++j) ones[j] = (bf16_t)1.0f;

  bf16x8 qf[2];   // q_buf NORMAL layout; [dc]
  {
    const size_t qrow = ((size_t)b * S_ + q0 + l16) * D_ + h * HD_;
    qf[0] = load8g(Q + qrow + quad * 8);
    qf[1] = load8g(Q + qrow + 32 + quad * 8);
  }

  f32x4 oacc[4] = {};
  f32x4 lacc = {};

  const size_t kbase = (size_t)b * S_ * D_ + h * HD_;
  const size_t vbase = ((size_t)(b * H_ + h)) * HD_ * S_;

  const int rbase = ((l16 >> 2) << 3) | (l16 & 3);
  int koff[2][4];   // [dc][j]
#pragma unroll
  for (int j = 0; j < 4; ++j) {
    const int rho = rbase + (j >> 1) * 32 + (j & 1) * 4;
#pragma unroll
    for (int dc = 0; dc < 2; ++dc)
      koff[dc][j] = rho * 64 + swcolK(dc * 32 + quad * 8, rho);
  }
  const int voff[2] = { swcol(quad * 8, l16), swcol(32 + quad * 8, l16) };

  auto stage = [&](int slot, int k0) {
    const int r = wave * 8;
    gl2lds(Kb + kbase + (size_t)(k0 + r + lr) * D_ + lc, &Ks[slot][r][0]);
    gl2lds(Vt + vbase + (size_t)(r + lr) * S_ + k0 + lc, &Vs[slot][r][0]);
  };

  constexpr float CE = 0.18033688011112042f;  // 0.125 * log2(e)

  auto compute = [&](int cur) {
    f32x4 sacc[4] = {};
    const bf16_t* ksbase = &Ks[cur][0][0];
#pragma unroll
    for (int dc = 0; dc < 2; ++dc) {
      bf16x8 kf[4];
#pragma unroll
      for (int j = 0; j < 4; ++j)
        kf[j] = *reinterpret_cast<const bf16x8*>(ksbase + koff[dc][j]);
#pragma unroll
      for (int j = 0; j < 4; ++j)
        sacc[j] = __builtin_amdgcn_mfma_f32_16x16x32_bf16(kf[j], qf[dc], sacc[j], 0, 0, 0);
    }
#pragma unroll
    for (int kc = 0; kc < 2; ++kc) {
      bf16x8 vf[4];
#pragma unroll
      for (int dj = 0; dj < 4; ++dj)
        vf[dj] = *reinterpret_cast<const bf16x8*>(&Vs[cur][dj * 16 + l16][voff[kc]]);
      bf16x8 bp;
#pragma unroll
      for (int r = 0; r < 4; ++r) {
        bp[r]     = (bf16_t)__builtin_amdgcn_exp2f(fminf(sacc[kc * 2][r]     * CE, 57.5f));
        bp[4 + r] = (bf16_t)__builtin_amdgcn_exp2f(fminf(sacc[kc * 2 + 1][r] * CE, 57.5f));
      }
#pragma unroll
      for (int dj = 0; dj < 4; ++dj)
        oacc[dj] = __builtin_amdgcn_mfma_f32_16x16x32_bf16(vf[dj], bp, oacc[dj], 0, 0, 0);
      lacc = __builtin_amdgcn_mfma_f32_16x16x32_bf16(ones, bp, lacc, 0, 0, 0);
    }
  };

  // drain Q loads once so the loop's vmcnt ledger counts only gl2lds ops
  asm volatile("s_waitcnt vmcnt(0)" ::: "memory");
  stage(0, 0);
  stage(1, 64);

  constexpr int NT = S_ / 64;   // 32
  int cur = 0;
  for (int kt = 0; kt < NT - 1; ++kt) {
    asm volatile("s_waitcnt vmcnt(2)\n\ts_barrier" ::: "memory");
    __builtin_amdgcn_sched_barrier(0);
    if (kt + 2 < NT) {
      const int slot2 = cur == 0 ? 2 : cur - 1;   // (kt+2)%3, freed at barrier above
      stage(slot2, (kt + 2) * 64);
    }
    compute(cur);
    cur = (cur == 2) ? 0 : cur + 1;
  }
  asm volatile("s_waitcnt vmcnt(0)\n\ts_barrier" ::: "memory");
  __builtin_amdgcn_sched_barrier(0);
  compute(cur);

  // ---- epilogue: O[q][d] = O^T[d][q] / l[q]; packed 8B stores, SWIZZLED (feeds g2) ----
  {
    const float linv = 1.0f / fmaxf(lacc[0], 1e-30f);
    const int q = q0 + l16;
    const size_t orow = ((size_t)b * S_ + q) * D_ + h * HD_;
#pragma unroll
    for (int dj = 0; dj < 4; ++dj) {
      bf16x4 pack;
#pragma unroll
      for (int r = 0; r < 4; ++r) pack[r] = (bf16_t)(oacc[dj][r] * linv);
      *reinterpret_cast<bf16x4*>(&O[orow + swcol(dj * 16 + quad * 4, q)]) = pack;
    }
  }
}

// ---------------- host launcher ----------------
extern "C" void kernel_launch(void* const* d_in, const int* in_sizes, int n_in,
                              void* d_out, int out_size, void* d_ws, size_t ws_size,
                              hipStream_t stream) {
  (void)n_in; (void)out_size; (void)ws_size;

  char* ws = (char*)d_ws;
  auto alloc = [&](size_t bytes) -> char* {
    char* p = ws; ws += (bytes + 255) & ~(size_t)255; return p;
  };
  int* flags = (int*)alloc(64 * sizeof(int));
  const size_t wbytes = (size_t)512 * 512 * sizeof(bf16_t);
  const size_t fbytes = (size_t)M_ * D_ * sizeof(bf16_t);
  bf16_t* wt    = (bf16_t*)alloc(6 * wbytes);  // 3 MB (swizzled)
  bf16_t* m1b   = (bf16_t*)alloc(fbytes);      // 8 MB mod1 bf16 swizzled; vtb alias after qproj
  bf16_t* m2b   = (bf16_t*)alloc(fbytes);      // 8 MB mod2 bf16 swizzled
  bf16_t* q_buf = (bf16_t*)alloc(fbytes);      // 8 MB normal
  bf16_t* atmp  = (bf16_t*)alloc(fbytes);      // 8 MB attn output (swizzled)
  bf16_t* kmod  = (bf16_t*)alloc(fbytes);      // 8 MB swizzled (swcolK)
  bf16_t* vtb    = m1b;    // alias: m1b dead after qproj
  bf16_t* attn_b = atmp;

  bf16_t* wtq  = wt + 0 * 512 * 512;
  bf16_t* wtk  = wt + 1 * 512 * 512;
  bf16_t* wtv  = wt + 2 * 512 * 512;
  bf16_t* wts  = wt + 3 * 512 * 512;
  bf16_t* wtsh = wt + 4 * 512 * 512;
  bf16_t* wto  = wt + 5 * 512 * 512;

  DetectArgs da;
  for (int i = 0; i < NIN; ++i) {
    da.p[i] = (const uint16_t*)d_in[i];
    da.n[i] = in_sizes[i] < 2048 ? in_sizes[i] : 2048;
  }
  da.flags = flags;
  hipLaunchKernelGGL(detect_kernel, dim3(NIN), dim3(64), 0, stream, da);

  // prep: cvt (4096 blocks) + weight transpose (384 blocks), one dispatch
  PrepArgs pa;
  pa.csrc[0] = d_in[0]; pa.cdst[0] = m1b; pa.cidx[0] = 0;
  pa.csrc[1] = d_in[1]; pa.cdst[1] = m2b; pa.cidx[1] = 1;
  const int widx[6] = {2, 4, 6, 10, 12, 8};
  bf16_t* wdst[6] = {wtq, wtk, wtv, wts, wtsh, wto};
  for (int i = 0; i < 6; ++i) { pa.wsrc[i] = d_in[widx[i]]; pa.wIdx[i] = widx[i]; pa.wdst[i] = wdst[i]; }
  pa.flags = flags;
  hipLaunchKernelGGL(prep_kernel, dim3(4096 + 384), dim3(256), 0, stream, pa);

  // qproj: Q projection only — 512 blocks x 512 thr, 3-slot pipeline
  GemmBatch g1;
  g1.A[0] = m1b;  g1.A[1] = m1b;  g1.A[2] = m1b;
  g1.Bt[0] = wtq; g1.Bt[1] = wtq; g1.Bt[2] = wtq;
  g1.bias[0] = d_in[3];  g1.bIdx[0] = 3;
  g1.bias[1] = d_in[3];  g1.bIdx[1] = 3;
  g1.bias[2] = d_in[3];  g1.bIdx[2] = 3;
  g1.C[0] = q_buf; g1.cIdx[0] = -1;
  g1.C[1] = q_buf; g1.cIdx[1] = -1;
  g1.C[2] = q_buf; g1.cIdx[2] = -1;
  g1.flags = flags;
  hipLaunchKernelGGL(gemm_bt_kernel, dim3(M_ / 128, 8, 1), dim3(512), 0, stream, g1);

  // ksv: fused K/V/scale/shift + modulation — 512 blocks x 1024 thr (4 waves/SIMD)
  KsvArgs kv;
  kv.A = m2b;
  kv.Bt[0] = wtk; kv.Bt[1] = wtv; kv.Bt[2] = wts; kv.Bt[3] = wtsh;
  kv.bias[0] = d_in[5];  kv.bIdx[0] = 5;
  kv.bias[1] = d_in[7];  kv.bIdx[1] = 7;
  kv.bias[2] = d_in[11]; kv.bIdx[2] = 11;
  kv.bias[3] = d_in[13]; kv.bIdx[3] = 13;
  kv.Kmod = kmod; kv.VtT = vtb;
  kv.flags = flags;
  hipLaunchKernelGGL(ksv_kernel, dim3(M_ / 128, 8), dim3(1024), 0, stream, kv);

  // attn: 512 blocks x 512 threads (v12), 3-slot pipeline, vmcnt(2)
  hipLaunchKernelGGL(attn_kernel, dim3(512), dim3(512), 0, stream,
                     q_buf, kmod, vtb, attn_b);

  // g2: out = attn @ Wo^T + bo — 512 blocks x 512 thr
  GemmBatch g2;
  for (int i = 0; i < 3; ++i) {
    g2.A[i] = attn_b;
    g2.Bt[i] = wto;
    g2.bias[i] = d_in[9]; g2.bIdx[i] = 9;
    g2.C[i] = d_out; g2.cIdx[i] = 0;
  }
  g2.flags = flags;
  hipLaunchKernelGGL(gemm_bt_kernel, dim3(M_ / 128, 8, 1), dim3(512), 0, stream, g2);
}